// Round 1
// baseline (475.880 us; speedup 1.0000x reference)
//
#include <hip/hip_runtime.h>
#include <math.h>

#define NHEAD 12
#define DH 64
#define S_LEN 4096
#define B_SZ 2
#define D_MODEL 768
#define FF_DIM 3072
#define WINSZ 128
#define NGLB 32
#define NEGV -1e9f
#define NQC 6291456L

typedef __attribute__((ext_vector_type(8))) short bf16x8;
typedef __attribute__((ext_vector_type(4))) float floatx4;

__device__ __forceinline__ unsigned short f2bf(float x) {
    union { float f; unsigned u; } v; v.f = x;
    unsigned r = v.u + 0x7fffu + ((v.u >> 16) & 1u);
    return (unsigned short)(r >> 16);
}
__device__ __forceinline__ float bf2f(unsigned short x) {
    union { unsigned u; float f; } v; v.u = ((unsigned)x) << 16;
    return v.f;
}

__device__ __forceinline__ void async_copy16(const unsigned short* g, unsigned short* l) {
    __builtin_amdgcn_global_load_lds(
        (const __attribute__((address_space(1))) void*)g,
        (__attribute__((address_space(3))) void*)l, 16, 0, 0);
}

// ---------------------------------------------------------------------------
// fp32 -> bf16 elementwise
// ---------------------------------------------------------------------------
__global__ __launch_bounds__(256) void conv_k(
    const float* __restrict__ x, unsigned short* __restrict__ y, long n)
{
    long i = ((long)blockIdx.x * 256 + threadIdx.x) * 4;
    if (i >= n) return;
    float4 v = *(const float4*)(x + i);
    ushort4 o;
    o.x = f2bf(v.x); o.y = f2bf(v.y); o.z = f2bf(v.z); o.w = f2bf(v.w);
    *(ushort4*)(y + i) = o;
}

// ---------------------------------------------------------------------------
// concat 3 x 768 biases -> 2304
// ---------------------------------------------------------------------------
__global__ __launch_bounds__(256) void bcat_k(
    const float* __restrict__ a, const float* __restrict__ b,
    const float* __restrict__ c, float* __restrict__ o)
{
    int i = blockIdx.x * 256 + threadIdx.x;
    if (i < 768) o[i] = a[i];
    else if (i < 1536) o[i] = b[i - 768];
    else if (i < 2304) o[i] = c[i - 1536];
}

// ---------------------------------------------------------------------------
// W (KxN fp32) -> WT (NxK bf16)
// ---------------------------------------------------------------------------
__global__ __launch_bounds__(256) void transpose_k(
    const float* __restrict__ W, unsigned short* __restrict__ WT, int K, int N)
{
    __shared__ float tile[32][33];
    const int tx = threadIdx.x, ty = threadIdx.y;
    const int n0 = blockIdx.x * 32, k0 = blockIdx.y * 32;
#pragma unroll
    for (int i = 0; i < 4; ++i)
        tile[ty + 8 * i][tx] = W[(long)(k0 + ty + 8 * i) * N + n0 + tx];
    __syncthreads();
#pragma unroll
    for (int i = 0; i < 4; ++i)
        WT[(long)(n0 + ty + 8 * i) * K + k0 + tx] = f2bf(tile[tx][ty + 8 * i]);
}

// ---------------------------------------------------------------------------
// V (B,NH,S,DH) bf16 -> Vt (B,NH,DH,S) bf16
// ---------------------------------------------------------------------------
__global__ __launch_bounds__(256) void vt_k(
    const unsigned short* __restrict__ v, unsigned short* __restrict__ vt)
{
    const int bh = blockIdx.y;
    const int s0 = blockIdx.x * 32;
    const int w = threadIdx.x >> 6, lane = threadIdx.x & 63;
    const unsigned short* src = v + ((long)bh * S_LEN + s0 + w * 8) * DH + lane;
    unsigned short r[8];
#pragma unroll
    for (int j = 0; j < 8; ++j) r[j] = src[j * DH];
    unsigned short* dst = vt + ((long)bh * DH + lane) * S_LEN + s0 + w * 8;
    ushort4 lo, hi;
    lo.x = r[0]; lo.y = r[1]; lo.z = r[2]; lo.w = r[3];
    hi.x = r[4]; hi.y = r[5]; hi.z = r[6]; hi.w = r[7];
    *(ushort4*)dst = lo;
    *(ushort4*)(dst + 4) = hi;
}

// ---------------------------------------------------------------------------
// 256x256-tile 8-phase bf16 MFMA GEMM (learn_hip m201 schedule, plain HIP).
// 512 thr / 8 waves (2M x 4N), BK=64, 128 KiB LDS double-buffer.
// LDS per buffer: A-units m=0/1 (16 KiB each: compute-rows interleaved so a
// unit is exactly the rows read in phases with that m), B-units n=0/1.
// st_16x32 swizzle: within each 1024B (16x32 bf16) subtile, byte5 ^= row-bit3.
// global_load_lds staging is linear-dest; the inverse swizzle is applied to
// the per-lane GLOBAL source address (rule 21).
// Issue schedule (group u computes tile u, buffer u&1):
//   P1(m0,n0): issue (u+1).A1   P2(m0,n1): issue (u+1).B1
//   P3(m1,n0): issue (u+2).A0   P4(m1,n1): issue (u+2).B0 ; s_waitcnt vmcnt(4)
// vmcnt(4) at group end == "everything except the newest 2 half-tiles landed"
// == tile u+1 fully resident. Never drains to 0 in steady state.
// EPI 0: split-K raw fp32 partials (slice = t8>=ntile, kbeg=K2)
// EPI 1: bias+gelu -> bf16
// EPI 2: fused QKV scatter (part=n/768; Q scaled 0.125) -> bf16
// ---------------------------------------------------------------------------
#define MFMA_QUAD(MM, NN, BREG)                                                \
    __builtin_amdgcn_s_setprio(1);                                             \
    _Pragma("unroll")                                                          \
    for (int f = 0; f < 4; ++f)                                                \
        _Pragma("unroll")                                                      \
        for (int g = 0; g < 2; ++g)                                            \
            _Pragma("unroll")                                                  \
            for (int ks = 0; ks < 2; ++ks)                                     \
                acc[(MM) * 4 + f][(NN) * 2 + g] =                              \
                    __builtin_amdgcn_mfma_f32_16x16x32_bf16(                   \
                        af[f][ks], BREG[g][ks], acc[(MM) * 4 + f][(NN) * 2 + g], 0, 0, 0); \
    __builtin_amdgcn_s_setprio(0);

template <int EPI>
__global__ __launch_bounds__(512, 2) void gemm8(
    const unsigned short* __restrict__ A, const unsigned short* __restrict__ BT,
    const float* __restrict__ bias, void* __restrict__ out, float* __restrict__ out1,
    int M, int N, int Kst, int K2, int nx, int ntile)
{
    __shared__ __align__(16) unsigned short As[32768];   // [buf][munit][8192]
    __shared__ __align__(16) unsigned short Bs[32768];   // [buf][nunit][8192]

    const int tid = threadIdx.x;
    const int w = tid >> 6, lane = tid & 63;
    int t8 = (blockIdx.x & 7) * (gridDim.x >> 3) + (blockIdx.x >> 3);
    int kbeg = 0;
    float* P = (float*)out;
    if (EPI == 0) {
        if (t8 >= ntile) { t8 -= ntile; kbeg = K2; P = out1; }
    }
    const int m0 = (t8 / nx) * 256, n0 = (t8 % nx) * 256;
    const int NT = K2 >> 6;

    const int wr = w >> 2, wc = w & 3;            // wave tile: rows wr*128, cols wc*64
    const int ln15 = lane & 15, ln4 = lane >> 4;
    const int wr8 = wr << 3, wc4 = wc << 2;

    // ---- staging: per-lane inverse-swizzled global source -----------------
    const int srow = lane >> 2;                                   // subtile row
    const int scol = ((lane & 3) << 3) ^ ((lane & 32) >> 1);      // bf16 col (inv swz)
    const int ruA = w * 16 + srow;                                // row within unit
    const int rA0 = ((ruA >> 6) << 7) + (ruA & 63);               // + m*64
    const int rB0 = ((ruA >> 5) << 6) + (ruA & 31);               // + n*32
    const unsigned short* gA[2];
    const unsigned short* gB[2];
    gA[0] = A + (long)(m0 + rA0) * Kst + kbeg + scol;
    gA[1] = A + (long)(m0 + rA0 + 64) * Kst + kbeg + scol;
    gB[0] = BT + (long)(n0 + rB0) * Kst + kbeg + scol;
    gB[1] = BT + (long)(n0 + rB0 + 32) * Kst + kbeg + scol;
    const int wld = w << 10;                       // wave's 2 subtiles (ushort idx)

    auto issueA = [&](int mu, int tt) {
        const unsigned short* g = gA[mu] + (long)tt * 64;
        unsigned short* l = &As[((((tt & 1) << 1) | mu) << 13) + wld];
        async_copy16(g, l);
        async_copy16(g + 32, l + 512);
    };
    auto issueB = [&](int nu, int tt) {
        const unsigned short* g = gB[nu] + (long)tt * 64;
        unsigned short* l = &Bs[((((tt & 1) << 1) | nu) << 13) + wld];
        async_copy16(g, l);
        async_copy16(g + 32, l + 512);
    };

    // ---- per-lane swizzled LDS read offset (ushort) -----------------------
    const int p2 = ((ln15 << 5) | (ln4 << 3)) ^ ((ln15 & 8) << 1);

    floatx4 acc[8][4];
#pragma unroll
    for (int i = 0; i < 8; ++i)
#pragma unroll
        for (int j = 0; j < 4; ++j) acc[i][j] = (floatx4){0.f, 0.f, 0.f, 0.f};
    bf16x8 af[4][2], b0[2][2], b1[2][2];

    // ---- prologue: tile0 {A0,B0,A1,B1}, tile1 {A0,B0} ---------------------
    issueA(0, 0); issueB(0, 0); issueA(1, 0); issueB(1, 0);
    if (NT > 1) {
        issueA(0, 1); issueB(0, 1);
        asm volatile("s_waitcnt vmcnt(4)" ::: "memory");
    } else {
        asm volatile("s_waitcnt vmcnt(0)" ::: "memory");
    }
    __builtin_amdgcn_s_barrier();
    __builtin_amdgcn_sched_barrier(0);

    for (int u = 0; u < NT; ++u) {
        const unsigned short* Ab = &As[((u & 1) << 14) + p2];
        const unsigned short* Bb = &Bs[((u & 1) << 14) + p2];

        // ---- P1 (m=0,n=0) -------------------------------------------------
#pragma unroll
        for (int f = 0; f < 4; ++f)
#pragma unroll
            for (int ks = 0; ks < 2; ++ks)
                af[f][ks] = *(const bf16x8*)(Ab + ((wr8 + f * 2 + ks) << 9));
#pragma unroll
        for (int g = 0; g < 2; ++g)
#pragma unroll
            for (int ks = 0; ks < 2; ++ks)
                b0[g][ks] = *(const bf16x8*)(Bb + ((wc4 + g * 2 + ks) << 9));
        if (u + 1 < NT) issueA(1, u + 1);
        __builtin_amdgcn_sched_barrier(0);
        __builtin_amdgcn_s_barrier();
        asm volatile("s_waitcnt lgkmcnt(0)" ::: "memory");
        __builtin_amdgcn_sched_barrier(0);
        MFMA_QUAD(0, 0, b0)
        __builtin_amdgcn_sched_barrier(0);
        __builtin_amdgcn_s_barrier();

        // ---- P2 (m=0,n=1) -------------------------------------------------
#pragma unroll
        for (int g = 0; g < 2; ++g)
#pragma unroll
            for (int ks = 0; ks < 2; ++ks)
                b1[g][ks] = *(const bf16x8*)(Bb + 8192 + ((wc4 + g * 2 + ks) << 9));
        if (u + 1 < NT) issueB(1, u + 1);
        __builtin_amdgcn_sched_barrier(0);
        __builtin_amdgcn_s_barrier();
        asm volatile("s_waitcnt lgkmcnt(0)" ::: "memory");
        __builtin_amdgcn_sched_barrier(0);
        MFMA_QUAD(0, 1, b1)
        __builtin_amdgcn_sched_barrier(0);
        __builtin_amdgcn_s_barrier();

        // ---- P3 (m=1,n=0) -------------------------------------------------
#pragma unroll
        for (int f = 0; f < 4; ++f)
#pragma unroll
            for (int ks = 0; ks < 2; ++ks)
                af[f][ks] = *(const bf16x8*)(Ab + 8192 + ((wr8 + f * 2 + ks) << 9));
        if (u + 2 < NT) issueA(0, u + 2);
        __builtin_amdgcn_sched_barrier(0);
        __builtin_amdgcn_s_barrier();
        asm volatile("s_waitcnt lgkmcnt(0)" ::: "memory");
        __builtin_amdgcn_sched_barrier(0);
        MFMA_QUAD(1, 0, b0)
        __builtin_amdgcn_sched_barrier(0);
        __builtin_amdgcn_s_barrier();

        // ---- P4 (m=1,n=1) -------------------------------------------------
        if (u + 2 < NT) issueB(0, u + 2);
        __builtin_amdgcn_sched_barrier(0);
        __builtin_amdgcn_s_barrier();
        asm volatile("s_waitcnt lgkmcnt(0)" ::: "memory");
        __builtin_amdgcn_sched_barrier(0);
        MFMA_QUAD(1, 1, b1)
        __builtin_amdgcn_sched_barrier(0);
        if (u + 2 < NT)      asm volatile("s_waitcnt vmcnt(4)" ::: "memory");
        else if (u + 1 < NT) asm volatile("s_waitcnt vmcnt(0)" ::: "memory");
        __builtin_amdgcn_s_barrier();
        __builtin_amdgcn_sched_barrier(0);
    }

    // ---- epilogue ---------------------------------------------------------
    const int col_l = lane & 15, row_l = ln4 << 2;
#pragma unroll
    for (int mi = 0; mi < 8; ++mi) {
        const int mbase = m0 + wr * 128 + ((mi >> 2) << 6) + ((mi & 3) << 4) + row_l;
#pragma unroll
        for (int ni = 0; ni < 4; ++ni) {
            const int n = n0 + wc * 64 + ((ni >> 1) << 5) + ((ni & 1) << 4) + col_l;
            if (EPI == 0) {
#pragma unroll
                for (int rg = 0; rg < 4; ++rg)
                    P[(long)(mbase + rg) * N + n] = acc[mi][ni][rg];
            } else if (EPI == 1) {
                const float bv = bias[n];
#pragma unroll
                for (int rg = 0; rg < 4; ++rg) {
                    float v = acc[mi][ni][rg] + bv;
                    v = 0.5f * v * (1.f + erff(v * 0.70710678118654752f));
                    ((unsigned short*)out)[(long)(mbase + rg) * N + n] = f2bf(v);
                }
            } else {
                const float bv = bias[n];
                const int part = n / 768;          // 0=q, 1=k, 2=v
                const int nn = n - part * 768;
                const int hh = nn >> 6, dh = nn & 63;
                const float sc = (part == 0) ? 0.125f : 1.f;
#pragma unroll
                for (int rg = 0; rg < 4; ++rg) {
                    const int m = mbase + rg;
                    const int bb = m >> 12, s = m & 4095;
                    ((unsigned short*)out)[(long)part * NQC +
                        (((long)bb * NHEAD + hh) * S_LEN + s) * DH + dh] =
                        f2bf((acc[mi][ni][rg] + bv) * sc);
                }
            }
        }
    }
}

// ---------------------------------------------------------------------------
// MFMA band attention. One block per (b,h,chunk); 4 waves x 32 queries.
// ---------------------------------------------------------------------------
__global__ __launch_bounds__(256) void band_mfma_k(
    const unsigned short* __restrict__ q, const unsigned short* __restrict__ k,
    const unsigned short* __restrict__ vt, const float* __restrict__ am,
    unsigned short* __restrict__ ctx)
{
    __shared__ unsigned short Ks[32 * 72];
    __shared__ unsigned short Vs[64 * 40];
    __shared__ unsigned short Ps[4][32 * 40];

    const int blk = blockIdx.x;
    const int c = blk & 31;
    const int h = (blk >> 5) % NHEAD;
    const int b = blk / (32 * NHEAD);
    const int tid = threadIdx.x;
    const int wave = tid >> 6, lane = tid & 63;
    const long bh = (long)b * NHEAD + h;

    const unsigned short* kh  = k + bh * S_LEN * DH;
    const unsigned short* vth = vt + bh * (long)DH * S_LEN;
    const float* amb = am + (long)b * S_LEN;

    const int q0 = c * WINSZ + wave * 32;
    const int ln15 = lane & 15, ln4 = lane >> 4;

    bf16x8 qf[2][2];
#pragma unroll
    for (int nt = 0; nt < 2; ++nt)
#pragma unroll
        for (int ks = 0; ks < 2; ++ks)
            qf[nt][ks] = *(const bf16x8*)(q + (bh * S_LEN + q0 + nt * 16 + ln15) * DH
                                          + ks * 32 + ln4 * 8);

    floatx4 o[4][2];
#pragma unroll
    for (int mt = 0; mt < 4; ++mt)
#pragma unroll
        for (int nt = 0; nt < 2; ++nt) o[mt][nt] = (floatx4){0.f, 0.f, 0.f, 0.f};
    float m_r[2] = {-1e30f, -1e30f}, l_r[2] = {0.f, 0.f};

    const int sk_key = tid >> 3, sk_ch = tid & 7;
    const int sv_dim = tid & 63, sv_ch = tid >> 6;
    const bf16x8 zero8 = {0, 0, 0, 0, 0, 0, 0, 0};

    for (int tile = 0; tile < 13; ++tile) {
        const bool glob = (tile == 12);
        const int kbase = glob ? 0 : (c * WINSZ - WINSZ + tile * 32);

        __syncthreads();
        {
            int kpos = kbase + sk_key;
            bf16x8 val = zero8;
            if ((unsigned)kpos < (unsigned)S_LEN)
                val = *(const bf16x8*)(kh + (long)kpos * DH + sk_ch * 8);
            *(bf16x8*)(&Ks[sk_key * 72 + sk_ch * 8]) = val;
        }
        {
            int kc = kbase + sv_ch * 8;
            bf16x8 val = zero8;
            if (kc >= 0 && kc + 8 <= S_LEN)
                val = *(const bf16x8*)(vth + (long)sv_dim * S_LEN + kc);
            *(bf16x8*)(&Vs[sv_dim * 40 + sv_ch * 8]) = val;
        }
        __syncthreads();

        bf16x8 ak[2][2];
#pragma unroll
        for (int mt = 0; mt < 2; ++mt)
#pragma unroll
            for (int ks = 0; ks < 2; ++ks)
                ak[mt][ks] = *(const bf16x8*)(&Ks[(mt * 16 + ln15) * 72 + ks * 32 + ln4 * 8]);

        floatx4 s[2][2];
#pragma unroll
        for (int mt = 0; mt < 2; ++mt)
#pragma unroll
            for (int nt = 0; nt < 2; ++nt) {
                floatx4 acc = (floatx4){0.f, 0.f, 0.f, 0.f};
                acc = __builtin_amdgcn_mfma_f32_16x16x32_bf16(ak[mt][0], qf[nt][0], acc, 0, 0, 0);
                acc = __builtin_amdgcn_mfma_f32_16x16x32_bf16(ak[mt][1], qf[nt][1], acc, 0, 0, 0);
                s[mt][nt] = acc;
            }

#pragma unroll
        for (int mt = 0; mt < 2; ++mt) {
            const int kp0 = kbase + mt * 16 + ln4 * 4;
#pragma unroll
            for (int rg = 0; rg < 4; ++rg) {
                const int kpos = kp0 + rg;
                const bool kin = (unsigned)kpos < (unsigned)S_LEN;
                const float amv = kin ? amb[kpos] : 0.f;
#pragma unroll
                for (int nt = 0; nt < 2; ++nt) {
                    const int qpos = q0 + nt * 16 + ln15;
                    const int dlt = kpos > qpos ? kpos - qpos : qpos - kpos;
                    const bool valid = glob || (kpos >= NGLB && kin && dlt <= WINSZ);
                    s[mt][nt][rg] = valid ? s[mt][nt][rg] + amv : NEGV;
                }
            }
        }

        float alpha[2];
#pragma unroll
        for (int nt = 0; nt < 2; ++nt) {
            float mx = s[0][nt][0];
#pragma unroll
            for (int rg = 1; rg < 4; ++rg) mx = fmaxf(mx, s[0][nt][rg]);
#pragma unroll
            for (int rg = 0; rg < 4; ++rg) mx = fmaxf(mx, s[1][nt][rg]);
            mx = fmaxf(mx, __shfl_xor(mx, 16));
            mx = fmaxf(mx, __shfl_xor(mx, 32));
            const float mn = fmaxf(m_r[nt], mx);
            alpha[nt] = __expf(m_r[nt] - mn);
            m_r[nt] = mn;
        }

#pragma unroll
        for (int nt = 0; nt < 2; ++nt) {
            float sum = 0.f;
#pragma unroll
            for (int mt = 0; mt < 2; ++mt) {
                ushort4 pk;
#pragma unroll
                for (int rg = 0; rg < 4; ++rg) {
                    const float p = __expf(s[mt][nt][rg] - m_r[nt]);
                    sum += p;
                    ((unsigned short*)&pk)[rg] = f2bf(p);
                }
                *(ushort4*)(&Ps[wave][(nt * 16 + ln15) * 40 + mt * 16 + ln4 * 4]) = pk;
            }
            sum += __shfl_xor(sum, 16);
            sum += __shfl_xor(sum, 32);
            l_r[nt] = l_r[nt] * alpha[nt] + sum;
        }

#pragma unroll
        for (int mt = 0; mt < 4; ++mt)
#pragma unroll
            for (int nt = 0; nt < 2; ++nt)
#pragma unroll
                for (int rg = 0; rg < 4; ++rg) o[mt][nt][rg] *= alpha[nt];

        bf16x8 av[4], bp[2];
#pragma unroll
        for (int mt = 0; mt < 4; ++mt)
            av[mt] = *(const bf16x8*)(&Vs[(mt * 16 + ln15) * 40 + ln4 * 8]);
#pragma unroll
        for (int nt = 0; nt < 2; ++nt)
            bp[nt] = *(const bf16x8*)(&Ps[wave][(nt * 16 + ln15) * 40 + ln4 * 8]);
#pragma unroll
        for (int mt = 0; mt < 4; ++mt)
#pragma unroll
            for (int nt = 0; nt < 2; ++nt)
                o[mt][nt] = __builtin_amdgcn_mfma_f32_16x16x32_bf16(
                    av[mt], bp[nt], o[mt][nt], 0, 0, 0);
    }

    const float inv0 = 1.f / l_r[0], inv1 = 1.f / l_r[1];
#pragma unroll
    for (int nt = 0; nt < 2; ++nt) {
        const float inv = nt ? inv1 : inv0;
        const long row = (long)b * S_LEN + q0 + nt * 16 + ln15;
#pragma unroll
        for (int mt = 0; mt < 4; ++mt) {
            ushort4 ov;
#pragma unroll
            for (int rg = 0; rg < 4; ++rg)
                ((unsigned short*)&ov)[rg] = f2bf(o[mt][nt][rg] * inv);
            *(ushort4*)(ctx + row * D_MODEL + h * DH + mt * 16 + ln4 * 4) = ov;
        }
    }
}

// ---------------------------------------------------------------------------
// MFMA global-query attention. One block per (b,h); 8 waves x 512 keys/iter.
// ---------------------------------------------------------------------------
__global__ __launch_bounds__(512) void glob_mfma_k(
    const unsigned short* __restrict__ q, const unsigned short* __restrict__ k,
    const unsigned short* __restrict__ vt, const float* __restrict__ am,
    unsigned short* __restrict__ ctx)
{
    __shared__ unsigned short Ps[8][32 * 72];
    __shared__ float Om[64 * 36];
    __shared__ float mW[8][32], lW[8][32], lTot[32];

    const int bh = blockIdx.x;
    const int b = bh / NHEAD, h = bh % NHEAD;
    const int tid = threadIdx.x;
    const int wave = tid >> 6, lane = tid & 63;
    const int ln15 = lane & 15, ln4 = lane >> 4;

    const unsigned short* kh  = k + (long)bh * S_LEN * DH;
    const unsigned short* vth = vt + (long)bh * DH * S_LEN;
    const float* amb = am + (long)b * S_LEN;

    bf16x8 qf[2][2];
#pragma unroll
    for (int nt = 0; nt < 2; ++nt)
#pragma unroll
        for (int ks = 0; ks < 2; ++ks)
            qf[nt][ks] = *(const bf16x8*)(q + ((long)bh * S_LEN + nt * 16 + ln15) * DH
                                          + ks * 32 + ln4 * 8);

    floatx4 o[4][2];
#pragma unroll
    for (int mt = 0; mt < 4; ++mt)
#pragma unroll
        for (int nt = 0; nt < 2; ++nt) o[mt][nt] = (floatx4){0.f, 0.f, 0.f, 0.f};
    float m_r[2] = {-1e30f, -1e30f}, l_r[2] = {0.f, 0.f};

    for (int it = 0; it < 8; ++it) {
        const int kbase = it * 512 + wave * 64;

        bf16x8 ak[4][2];
#pragma unroll
        for (int mt = 0; mt < 4; ++mt)
#pragma unroll
            for (int ks = 0; ks < 2; ++ks)
                ak[mt][ks] = *(const bf16x8*)(kh + (long)(kbase + mt * 16 + ln15) * DH
                                              + ks * 32 + ln4 * 8);

        floatx4 s[4][2];
#pragma unroll
        for (int mt = 0; mt < 4; ++mt)
#pragma unroll
            for (int nt = 0; nt < 2; ++nt) {
                floatx4 acc = (floatx4){0.f, 0.f, 0.f, 0.f};
                acc = __builtin_amdgcn_mfma_f32_16x16x32_bf16(ak[mt][0], qf[nt][0], acc, 0, 0, 0);
                acc = __builtin_amdgcn_mfma_f32_16x16x32_bf16(ak[mt][1], qf[nt][1], acc, 0, 0, 0);
                s[mt][nt] = acc;
            }

#pragma unroll
        for (int mt = 0; mt < 4; ++mt) {
            const int kp0 = kbase + mt * 16 + ln4 * 4;
#pragma unroll
            for (int rg = 0; rg < 4; ++rg) {
                const float amv = amb[kp0 + rg];
#pragma unroll
                for (int nt = 0; nt < 2; ++nt) s[mt][nt][rg] += amv;
            }
        }

        float alpha[2];
#pragma unroll
        for (int nt = 0; nt < 2; ++nt) {
            float mx = s[0][nt][0];
#pragma unroll
            for (int mt = 0; mt < 4; ++mt)
#pragma unroll
                for (int rg = 0; rg < 4; ++rg) mx = fmaxf(mx, s[mt][nt][rg]);
            mx = fmaxf(mx, __shfl_xor(mx, 16));
            mx = fmaxf(mx, __shfl_xor(mx, 32));
            const float mn = fmaxf(m_r[nt], mx);
            alpha[nt] = __expf(m_r[nt] - mn);
            m_r[nt] = mn;
        }

#pragma unroll
        for (int nt = 0; nt < 2; ++nt) {
            float sum = 0.f;
#pragma unroll
            for (int mt = 0; mt < 4; ++mt) {
                ushort4 pk;
#pragma unroll
                for (int rg = 0; rg < 4; ++rg) {
                    const float p = __expf(s[mt][nt][rg] - m_r[nt]);
                    sum += p;
                    ((unsigned short*)&pk)[rg] = f2bf(p);
                }
                *(ushort4*)(&Ps[wave][(nt * 16 + ln15) * 72 + mt * 16 + ln4 * 4]) = pk;
            }
            sum += __shfl_xor(sum, 16);
            sum += __shfl_xor(sum, 32);
            l_r[nt] = l_r[nt] * alpha[nt] + sum;
        }

#pragma unroll
        for (int mt = 0; mt < 4; ++mt)
#pragma unroll
            for (int nt = 0; nt < 2; ++nt)
#pragma unroll
                for (int rg = 0; rg < 4; ++rg) o[mt][nt][rg] *= alpha[nt];

        bf16x8 av[4][2], bp[2][2];
#pragma unroll
        for (int mt = 0; mt < 4; ++mt)
#pragma unroll
            for (int ks = 0; ks < 2; ++ks)
                av[mt][ks] = *(const bf16x8*)(vth + (long)(mt * 16 + ln15) * S_LEN
                                              + kbase + ks * 32 + ln4 * 8);
#pragma unroll
        for (int nt = 0; nt < 2; ++nt)
#pragma unroll
            for (int ks = 0; ks < 2; ++ks)
                bp[nt][ks] = *(const bf16x8*)(&Ps[wave][(nt * 16 + ln15) * 72
                                              + ks * 32 + ln4 * 8]);
#pragma unroll
        for (int mt = 0; mt < 4; ++mt)
#pragma unroll
            for (int nt = 0; nt < 2; ++nt) {
                o[mt][nt] = __builtin_amdgcn_mfma_f32_16x16x32_bf16(
                    av[mt][0], bp[nt][0], o[mt][nt], 0, 0, 0);
                o[mt][nt] = __builtin_amdgcn_mfma_f32_16x16x32_bf16(
                    av[mt][1], bp[nt][1], o[mt][nt], 0, 0, 0);
            }
    }

    if (ln4 == 0) {
#pragma unroll
        for (int nt = 0; nt < 2; ++nt) {
            mW[wave][nt * 16 + ln15] = m_r[nt];
            lW[wave][nt * 16 + ln15] = l_r[nt];
        }
    }
    for (int i = tid; i < 64 * 36; i += 512) Om[i] = 0.f;
    __syncthreads();

    float f[2];
#pragma unroll
    for (int nt = 0; nt < 2; ++nt) {
        const int qq = nt * 16 + ln15;
        float mt_ = mW[0][qq];
#pragma unroll
        for (int w = 1; w < 8; ++w) mt_ = fmaxf(mt_, mW[w][qq]);
        float lt = 0.f;
#pragma unroll
        for (int w = 0; w < 8; ++w) lt += __expf(mW[w][qq] - mt_) * lW[w][qq];
        f[nt] = __expf(m_r[nt] - mt_);
        if (wave == 0 && ln4 == 0) lTot[qq] = lt;
    }
#pragma unroll
    for (int mt = 0; mt < 4; ++mt)
#pragma unroll
        for (int nt = 0; nt < 2; ++nt)
#pragma unroll
            for (int rg = 0; rg < 4; ++rg) o[mt][nt][rg] *= f[nt];

    for (int wv = 0; wv < 8; ++wv) {
        if (wave == wv) {
#pragma unroll
            for (int mt = 0; mt < 4; ++mt)
#pragma unroll
                for (int nt = 0; nt < 2; ++nt)
#pragma unroll
                    for (int rg = 0; rg < 4; ++rg)
                        Om[(mt * 16 + ln4 * 4 + rg) * 36 + nt * 16 + ln15] += o[mt][nt][rg];
        }
        __syncthreads();
    }

    const int qq = tid >> 4, d0 = (tid & 15) * 4;
    const float inv = 1.f / lTot[qq];
    ushort4 ov;
#pragma unroll
    for (int i = 0; i < 4; ++i)
        ((unsigned short*)&ov)[i] = f2bf(Om[(d0 + i) * 36 + qq] * inv);
    *(ushort4*)(ctx + ((long)b * S_LEN + qq) * D_MODEL + h * DH + d0) = ov;
}

// ---------------------------------------------------------------------------
// Fused split-K reduce + bias + residual + LayerNorm. x = p0+p1+bias+resid.
// One block per row (768 cols). Optional bf16 copy.
// ---------------------------------------------------------------------------
__global__ __launch_bounds__(256) void ln2p_k(
    const float* __restrict__ p0, const float* __restrict__ p1,
    const float* __restrict__ bias, const float* __restrict__ resid,
    float* __restrict__ out, unsigned short* __restrict__ out_bf,
    const float* __restrict__ gw, const float* __restrict__ bw)
{
    __shared__ float red[256];
    const long row = blockIdx.x;
    const long base = row * D_MODEL;
    const int t = threadIdx.x;
    float v0 = p0[base + t]       + p1[base + t]       + bias[t]       + resid[base + t];
    float v1 = p0[base + t + 256] + p1[base + t + 256] + bias[t + 256] + resid[base + t + 256];
    float v2 = p0[base + t + 512] + p1[base + t + 512] + bias[t + 512] + resid[base + t + 512];

    red[t] = v0 + v1 + v2;
    __syncthreads();
    for (int off = 128; off; off >>= 1) {
        if (t < off) red[t] += red[t + off];
        __syncthreads();
    }
    const float mu = red[0] * (1.f / 768.f);
    __syncthreads();

    float d0 = v0 - mu, d1 = v1 - mu, d2 = v2 - mu;
    red[t] = d0 * d0 + d1 * d1 + d2 * d2;
    __syncthreads();
    for (int off = 128; off; off >>= 1) {
        if (t < off) red[t] += red[t + off];
        __syncthreads();
    }
    const float var = red[0] * (1.f / 768.f);
    const float rs = rsqrtf(var + 1e-12f);

    const float y0 = d0 * rs * gw[t] + bw[t];
    const float y1 = d1 * rs * gw[t + 256] + bw[t + 256];
    const float y2 = d2 * rs * gw[t + 512] + bw[t + 512];
    if (out) {
        float* y = out + base;
        y[t] = y0; y[t + 256] = y1; y[t + 512] = y2;
    }
    if (out_bf) {
        unsigned short* yb = out_bf + base;
        yb[t] = f2bf(y0); yb[t + 256] = f2bf(y1); yb[t + 512] = f2bf(y2);
    }
}

// ---------------------------------------------------------------------------
extern "C" void kernel_launch(void* const* d_in, const int* in_sizes, int n_in,
                              void* d_out, int out_size, void* d_ws, size_t ws_size,
                              hipStream_t stream)
{
    const float* hid  = (const float*)d_in[0];
    const float* am   = (const float*)d_in[1];
    const float* Wq   = (const float*)d_in[2];
    const float* bq   = (const float*)d_in[3];
    const float* Wk   = (const float*)d_in[4];
    const float* bk   = (const float*)d_in[5];
    const float* Wv   = (const float*)d_in[6];
    const float* bv   = (const float*)d_in[7];
    const float* Wo   = (const float*)d_in[8];
    const float* bo   = (const float*)d_in[9];
    const float* ln1g = (const float*)d_in[10];
    const float* ln1b = (const float*)d_in[11];
    const float* Wi   = (const float*)d_in[12];
    const float* bi   = (const float*)d_in[13];
    const float* Wo2  = (const float*)d_in[14];
    const float* bo2  = (const float*)d_in[15];
    const float* ln2g = (const float*)d_in[16];
    const float* ln2b = (const float*)d_in[17];

    const long M  = (long)B_SZ * S_LEN;                 // 8192
    const long NQ = NQC;                                // 6291456

    unsigned short* W16 = (unsigned short*)d_ws;
    unsigned short* qb   = W16;             // bf16 (B,NH,S,DH) — q|k|v contiguous
    unsigned short* kb   = W16 + NQ;
    unsigned short* vb   = W16 + 2 * NQ;
    unsigned short* vtb  = W16 + 3 * NQ;    // bf16 (B,NH,DH,S)
    unsigned short* ctxb = W16 + 4 * NQ;    // bf16 (B,S,768)
    unsigned short* hidb = W16 + 5 * NQ;    // bf16 hidden
    unsigned short* wqt  = W16 + 6 * NQ;    // [Wq|Wk|Wv]^T contiguous 2304x768
    unsigned short* wkt  = wqt + 589824;
    unsigned short* wvt  = wkt + 589824;
    unsigned short* wot  = wvt + 589824;
    unsigned short* wit  = wot + 589824;    // 2359296
    unsigned short* wo2t = wit + 2359296;   // 2359296 -> ends at u16 44826624
    float* tmp   = (float*)(W16 + 44826624);  // attn_out fp32 -> ends u16 57409536
    float* partB1 = (float*)(W16 + 57409536); // Wo2 split slice1 -> ends u16 69992448
    float* bcat  = (float*)(W16 + 69992448);  // 2304 fp32
    // aliases over dead regions:
    float* partA0 = (float*)W16;                  // Wo slice0 (over qb,kb)
    float* partA1 = (float*)(W16 + 2 * NQ);       // Wo slice1 (over vb,vtb)
    unsigned short* interb = W16;                 // Wi out (over qb..vtb)
    unsigned short* attnb  = hidb;                // LN1 bf16 (over hidb)
    float* partB0 = (float*)(W16 + 4 * NQ);       // Wo2 slice0 (over ctxb,hidb)
    (void)ws_size; (void)in_sizes; (void)n_in; (void)out_size;

    transpose_k<<<dim3(24, 24), dim3(32, 8), 0, stream>>>(Wq, wqt, 768, 768);
    transpose_k<<<dim3(24, 24), dim3(32, 8), 0, stream>>>(Wk, wkt, 768, 768);
    transpose_k<<<dim3(24, 24), dim3(32, 8), 0, stream>>>(Wv, wvt, 768, 768);
    transpose_k<<<dim3(24, 24), dim3(32, 8), 0, stream>>>(Wo, wot, 768, 768);
    transpose_k<<<dim3(96, 24), dim3(32, 8), 0, stream>>>(Wi, wit, 768, 3072);
    transpose_k<<<dim3(24, 96), dim3(32, 8), 0, stream>>>(Wo2, wo2t, 3072, 768);
    conv_k<<<dim3((NQ / 4 + 255) / 256), dim3(256), 0, stream>>>(hid, hidb, NQ);
    bcat_k<<<dim3(9), dim3(256), 0, stream>>>(bq, bk, bv, bcat);

    // fused QKV: one 256^2 8-phase GEMM, N = 2304, scatter to qb/kb/vb
    gemm8<2><<<dim3(288), dim3(512), 0, stream>>>(hidb, wqt, bcat, qb, nullptr,
                                                  (int)M, 2304, 768, 768, 9, 0);

    vt_k<<<dim3(128, 24), dim3(256), 0, stream>>>(vb, vtb);

    band_mfma_k<<<dim3(768), dim3(256), 0, stream>>>(qb, kb, vtb, am, ctxb);
    glob_mfma_k<<<dim3(B_SZ * NHEAD), dim3(512), 0, stream>>>(qb, kb, vtb, am, ctxb);

    // Wo split-K x2 -> partA0/partA1 ; LN1 fuses reduce+bias+resid
    gemm8<0><<<dim3(192), dim3(512), 0, stream>>>(ctxb, wot, nullptr, partA0, partA1,
                                                  (int)M, 768, 768, 384, 3, 96);
    ln2p_k<<<dim3(M), dim3(256), 0, stream>>>(partA0, partA1, bo, hid,
                                              tmp, attnb, ln1g, ln1b);

    // inter = gelu(attn_out @ Wi + bi)
    gemm8<1><<<dim3(384), dim3(512), 0, stream>>>(attnb, wit, bi, interb, nullptr,
                                                  (int)M, 3072, 768, 768, 12, 0);

    // Wo2 split-K x2 -> partB0/partB1 ; LN2 fuses reduce+bias+resid
    gemm8<0><<<dim3(192), dim3(512), 0, stream>>>(interb, wo2t, nullptr, partB0, partB1,
                                                  (int)M, 768, 3072, 1536, 3, 96);
    ln2p_k<<<dim3(M), dim3(256), 0, stream>>>(partB0, partB1, bo2, tmp,
                                              (float*)d_out, nullptr, ln2g, ln2b);
}

// Round 2
// 422.012 us; speedup vs baseline: 1.1276x; 1.1276x over previous
//
#include <hip/hip_runtime.h>
#include <math.h>

#define NHEAD 12
#define DH 64
#define S_LEN 4096
#define B_SZ 2
#define D_MODEL 768
#define FF_DIM 3072
#define WINSZ 128
#define NGLB 32
#define NEGV -1e9f
#define NQC 6291456L

typedef __attribute__((ext_vector_type(8))) short bf16x8;
typedef __attribute__((ext_vector_type(4))) float floatx4;

__device__ __forceinline__ unsigned short f2bf(float x) {
    union { float f; unsigned u; } v; v.f = x;
    unsigned r = v.u + 0x7fffu + ((v.u >> 16) & 1u);
    return (unsigned short)(r >> 16);
}
__device__ __forceinline__ float bf2f(unsigned short x) {
    union { unsigned u; float f; } v; v.u = ((unsigned)x) << 16;
    return v.f;
}

__device__ __forceinline__ void async_copy16(const unsigned short* g, unsigned short* l) {
    __builtin_amdgcn_global_load_lds(
        (const __attribute__((address_space(1))) void*)g,
        (__attribute__((address_space(3))) void*)l, 16, 0, 0);
}

// ---------------------------------------------------------------------------
// Fused prep: 6 weight transposes (fp32 KxN -> bf16 NxK, Wq scaled 0.125)
// + bias concat (bq scaled 0.125) + hidden fp32->bf16 conversion.
// Block ranges: [0,6912) transposes, [6912,6921) bcat, [6921,13065) conv.
// ---------------------------------------------------------------------------
__global__ __launch_bounds__(256) void prep_k(
    const float* __restrict__ Wq, const float* __restrict__ Wk,
    const float* __restrict__ Wv, const float* __restrict__ Wo,
    const float* __restrict__ Wi, const float* __restrict__ Wo2,
    unsigned short* __restrict__ wqt, unsigned short* __restrict__ wkt,
    unsigned short* __restrict__ wvt, unsigned short* __restrict__ wot,
    unsigned short* __restrict__ wit, unsigned short* __restrict__ wo2t,
    const float* __restrict__ bq, const float* __restrict__ bk,
    const float* __restrict__ bv, float* __restrict__ bcat,
    const float* __restrict__ hid, unsigned short* __restrict__ hidb)
{
    __shared__ float tile[32][33];
    const int bid = blockIdx.x;
    const int tx = threadIdx.x, ty = threadIdx.y;

    if (bid < 6912) {
        const float* src; unsigned short* dst; int K, N, nx, local; float scale = 1.f;
        if (bid < 576)       { src = Wq;  dst = wqt;  K = 768;  N = 768;  nx = 24; local = bid;        scale = 0.125f; }
        else if (bid < 1152) { src = Wk;  dst = wkt;  K = 768;  N = 768;  nx = 24; local = bid - 576;  }
        else if (bid < 1728) { src = Wv;  dst = wvt;  K = 768;  N = 768;  nx = 24; local = bid - 1152; }
        else if (bid < 2304) { src = Wo;  dst = wot;  K = 768;  N = 768;  nx = 24; local = bid - 1728; }
        else if (bid < 4608) { src = Wi;  dst = wit;  K = 768;  N = 3072; nx = 96; local = bid - 2304; }
        else                 { src = Wo2; dst = wo2t; K = 3072; N = 768;  nx = 24; local = bid - 4608; }
        const int n0 = (local % nx) * 32, k0 = (local / nx) * 32;
#pragma unroll
        for (int i = 0; i < 4; ++i)
            tile[ty + 8 * i][tx] = src[(long)(k0 + ty + 8 * i) * N + n0 + tx];
        __syncthreads();
#pragma unroll
        for (int i = 0; i < 4; ++i)
            dst[(long)(n0 + ty + 8 * i) * K + k0 + tx] = f2bf(tile[tx][ty + 8 * i] * scale);
    } else if (bid < 6921) {
        const int t = ty * 32 + tx;
        const int i = (bid - 6912) * 256 + t;
        if (i < 768) bcat[i] = bq[i] * 0.125f;
        else if (i < 1536) bcat[i] = bk[i - 768];
        else if (i < 2304) bcat[i] = bv[i - 1536];
    } else {
        const int t = ty * 32 + tx;
        const long i = ((long)(bid - 6921) * 256 + t) * 4;
        float4 v = *(const float4*)(hid + i);
        ushort4 o;
        o.x = f2bf(v.x); o.y = f2bf(v.y); o.z = f2bf(v.z); o.w = f2bf(v.w);
        *(ushort4*)(hidb + i) = o;
    }
}

// ---------------------------------------------------------------------------
// V (B,NH,S,DH) bf16 -> Vt (B,NH,DH,S) bf16
// ---------------------------------------------------------------------------
__global__ __launch_bounds__(256) void vt_k(
    const unsigned short* __restrict__ v, unsigned short* __restrict__ vt)
{
    const int bh = blockIdx.y;
    const int s0 = blockIdx.x * 32;
    const int w = threadIdx.x >> 6, lane = threadIdx.x & 63;
    const unsigned short* src = v + ((long)bh * S_LEN + s0 + w * 8) * DH + lane;
    unsigned short r[8];
#pragma unroll
    for (int j = 0; j < 8; ++j) r[j] = src[j * DH];
    unsigned short* dst = vt + ((long)bh * DH + lane) * S_LEN + s0 + w * 8;
    ushort4 lo, hi;
    lo.x = r[0]; lo.y = r[1]; lo.z = r[2]; lo.w = r[3];
    hi.x = r[4]; hi.y = r[5]; hi.z = r[6]; hi.w = r[7];
    *(ushort4*)dst = lo;
    *(ushort4*)(dst + 4) = hi;
}

// ---------------------------------------------------------------------------
// bf16 MFMA GEMM: C = epi(A @ BT^T + bias). XCD-clustered 1D swizzle.
// XOR LDS swizzle: staged chunk = (lane&3)^(srow&3) halves ds_read bank
// conflicts (8-way -> 4-way); read col = ((lane>>4)^(lane&3))*8.
// EPI 1: gelu -> bf16
// EPI 2: fused QKV scatter: part=n/768 (q|k|v) -> bf16 (Q scale pre-folded)
// ---------------------------------------------------------------------------
template <int EPI>
__global__ __launch_bounds__(256) void gemm_bf(
    const unsigned short* __restrict__ A, const unsigned short* __restrict__ BT,
    const float* __restrict__ bias, void* __restrict__ out,
    int M, int N, int K, int nx)
{
    __shared__ unsigned short As[128 * 32];
    __shared__ unsigned short Bs[128 * 32];
    const int tid = threadIdx.x;
    const int wave = tid >> 6, lane = tid & 63;
    const int t8 = (blockIdx.x & 7) * (gridDim.x >> 3) + (blockIdx.x >> 3);
    const int m0 = (t8 / nx) * 128, n0 = (t8 % nx) * 128;
    const int wr = (wave >> 1) * 64, wc = (wave & 1) * 64;

    floatx4 acc[4][4];
#pragma unroll
    for (int i = 0; i < 4; ++i)
#pragma unroll
        for (int j = 0; j < 4; ++j) acc[i][j] = (floatx4){0.f, 0.f, 0.f, 0.f};

    const int srow = lane >> 2;
    const int schk = (((lane & 3) ^ (srow & 3))) * 8;   // XOR-swizzled stage
    const int r = lane & 15;
    const int q8 = ((lane >> 4) ^ (lane & 3)) * 8;      // XOR-swizzled read

    for (int k0 = 0; k0 < K; k0 += 32) {
#pragma unroll
        for (int gi = 0; gi < 2; ++gi) {
            const int g = wave * 2 + gi;
            async_copy16(A + (long)(m0 + g * 16 + srow) * K + k0 + schk, &As[g * 512]);
            async_copy16(BT + (long)(n0 + g * 16 + srow) * K + k0 + schk, &Bs[g * 512]);
        }
        __syncthreads();

        bf16x8 af[4], bfr[4];
#pragma unroll
        for (int i = 0; i < 4; ++i) {
            af[i]  = *(const bf16x8*)&As[(wr + i * 16 + r) * 32 + q8];
            bfr[i] = *(const bf16x8*)&Bs[(wc + i * 16 + r) * 32 + q8];
        }
#pragma unroll
        for (int i = 0; i < 4; ++i)
#pragma unroll
            for (int j = 0; j < 4; ++j)
                acc[i][j] = __builtin_amdgcn_mfma_f32_16x16x32_bf16(
                    af[i], bfr[j], acc[i][j], 0, 0, 0);
        __syncthreads();
    }

    const int col_l = lane & 15, row_l = (lane >> 4) * 4;
#pragma unroll
    for (int i = 0; i < 4; ++i) {
#pragma unroll
        for (int j = 0; j < 4; ++j) {
            const int n = n0 + wc + j * 16 + col_l;
            const float bv = bias[n];
#pragma unroll
            for (int rg = 0; rg < 4; ++rg) {
                const int m = m0 + wr + i * 16 + row_l + rg;
                float v = acc[i][j][rg] + bv;
                if (EPI == 1) {
                    v = 0.5f * v * (1.f + erff(v * 0.70710678118654752f));
                    ((unsigned short*)out)[(long)m * N + n] = f2bf(v);
                } else {
                    const int bb = m >> 12, s = m & 4095;
                    const int part = n / 768;          // 0=q, 1=k, 2=v
                    const int nn = n - part * 768;
                    const int hh = nn >> 6, dh = nn & 63;
                    ((unsigned short*)out)[(long)part * NQC +
                        (((long)bb * NHEAD + hh) * S_LEN + s) * DH + dh] = f2bf(v);
                }
            }
        }
    }
}

// ---------------------------------------------------------------------------
// Split-K (x2) bf16 MFMA GEMM: raw fp32 partials, no epilogue. Grid =
// 2*ntile blocks; t8 < ntile -> slice 0 (k in [0,K2)), else slice 1.
// Reduction happens inside ln2p_k.
// ---------------------------------------------------------------------------
__global__ __launch_bounds__(256) void gemm_sp(
    const unsigned short* __restrict__ A, const unsigned short* __restrict__ BT,
    float* __restrict__ p0, float* __restrict__ p1,
    int M, int N, int K2, int nx, int ntile)
{
    __shared__ unsigned short As[128 * 32];
    __shared__ unsigned short Bs[128 * 32];
    const int tid = threadIdx.x;
    const int wave = tid >> 6, lane = tid & 63;
    const int t8 = (blockIdx.x & 7) * (gridDim.x >> 3) + (blockIdx.x >> 3);
    const int slice = t8 >= ntile;
    const int tile = t8 - slice * ntile;
    const int m0 = (tile / nx) * 128, n0 = (tile % nx) * 128;
    const int kbeg = slice * K2, kend = kbeg + K2;
    float* P = slice ? p1 : p0;
    const int wr = (wave >> 1) * 64, wc = (wave & 1) * 64;

    floatx4 acc[4][4];
#pragma unroll
    for (int i = 0; i < 4; ++i)
#pragma unroll
        for (int j = 0; j < 4; ++j) acc[i][j] = (floatx4){0.f, 0.f, 0.f, 0.f};

    const int srow = lane >> 2;
    const int schk = (((lane & 3) ^ (srow & 3))) * 8;
    const int r = lane & 15;
    const int q8 = ((lane >> 4) ^ (lane & 3)) * 8;
    const long Kl = (long)K2 * 2;

    for (int k0 = kbeg; k0 < kend; k0 += 32) {
#pragma unroll
        for (int gi = 0; gi < 2; ++gi) {
            const int g = wave * 2 + gi;
            async_copy16(A + (long)(m0 + g * 16 + srow) * Kl + k0 + schk, &As[g * 512]);
            async_copy16(BT + (long)(n0 + g * 16 + srow) * Kl + k0 + schk, &Bs[g * 512]);
        }
        __syncthreads();

        bf16x8 af[4], bfr[4];
#pragma unroll
        for (int i = 0; i < 4; ++i) {
            af[i]  = *(const bf16x8*)&As[(wr + i * 16 + r) * 32 + q8];
            bfr[i] = *(const bf16x8*)&Bs[(wc + i * 16 + r) * 32 + q8];
        }
#pragma unroll
        for (int i = 0; i < 4; ++i)
#pragma unroll
            for (int j = 0; j < 4; ++j)
                acc[i][j] = __builtin_amdgcn_mfma_f32_16x16x32_bf16(
                    af[i], bfr[j], acc[i][j], 0, 0, 0);
        __syncthreads();
    }

    const int col_l = lane & 15, row_l = (lane >> 4) * 4;
#pragma unroll
    for (int i = 0; i < 4; ++i)
#pragma unroll
        for (int j = 0; j < 4; ++j) {
            const int n = n0 + wc + j * 16 + col_l;
#pragma unroll
            for (int rg = 0; rg < 4; ++rg) {
                const int m = m0 + wr + i * 16 + row_l + rg;
                P[(long)m * N + n] = acc[i][j][rg];
            }
        }
}

// ---------------------------------------------------------------------------
// Fused attention: blocks [0,24) = global-query path (4 waves, 16 iters),
// blocks [24,792) = band path (b,h,chunk; 4 waves x 32 queries).
// Glob blocks launch FIRST so they overlap the band wave-front.
// Band suppresses stores for q0 < NGLB (those rows belong to glob) -> no race.
// ---------------------------------------------------------------------------
__global__ __launch_bounds__(256) void attn_k(
    const unsigned short* __restrict__ q, const unsigned short* __restrict__ k,
    const unsigned short* __restrict__ vt, const float* __restrict__ am,
    unsigned short* __restrict__ ctx)
{
    __shared__ __align__(16) unsigned char smem[28800];
    const int blk = blockIdx.x;
    const int tid = threadIdx.x;
    const int wave = tid >> 6, lane = tid & 63;
    const int ln15 = lane & 15, ln4 = lane >> 4;

    if (blk >= 24) {
        // ---------------- band path ----------------
        unsigned short* Ks = (unsigned short*)smem;            // 32*72
        unsigned short* Vs = Ks + 32 * 72;                     // 64*40
        unsigned short* Ps = Vs + 64 * 40;                     // [4][32*40]

        const int bb = blk - 24;
        const int c = bb & 31;
        const int h = (bb >> 5) % NHEAD;
        const int b = bb / (32 * NHEAD);
        const long bh = (long)b * NHEAD + h;

        const unsigned short* kh  = k + bh * S_LEN * DH;
        const unsigned short* vth = vt + bh * (long)DH * S_LEN;
        const float* amb = am + (long)b * S_LEN;

        const int q0 = c * WINSZ + wave * 32;

        bf16x8 qf[2][2];
#pragma unroll
        for (int nt = 0; nt < 2; ++nt)
#pragma unroll
            for (int ks = 0; ks < 2; ++ks)
                qf[nt][ks] = *(const bf16x8*)(q + (bh * S_LEN + q0 + nt * 16 + ln15) * DH
                                              + ks * 32 + ln4 * 8);

        floatx4 o[4][2];
#pragma unroll
        for (int mt = 0; mt < 4; ++mt)
#pragma unroll
            for (int nt = 0; nt < 2; ++nt) o[mt][nt] = (floatx4){0.f, 0.f, 0.f, 0.f};
        float m_r[2] = {-1e30f, -1e30f}, l_r[2] = {0.f, 0.f};

        const int sk_key = tid >> 3, sk_ch = tid & 7;
        const int sv_dim = tid & 63, sv_ch = tid >> 6;
        const bf16x8 zero8 = {0, 0, 0, 0, 0, 0, 0, 0};

        for (int tile = 0; tile < 13; ++tile) {
            const bool glob = (tile == 12);
            const int kbase = glob ? 0 : (c * WINSZ - WINSZ + tile * 32);

            __syncthreads();
            {
                int kpos = kbase + sk_key;
                bf16x8 val = zero8;
                if ((unsigned)kpos < (unsigned)S_LEN)
                    val = *(const bf16x8*)(kh + (long)kpos * DH + sk_ch * 8);
                *(bf16x8*)(&Ks[sk_key * 72 + sk_ch * 8]) = val;
            }
            {
                int kc = kbase + sv_ch * 8;
                bf16x8 val = zero8;
                if (kc >= 0 && kc + 8 <= S_LEN)
                    val = *(const bf16x8*)(vth + (long)sv_dim * S_LEN + kc);
                *(bf16x8*)(&Vs[sv_dim * 40 + sv_ch * 8]) = val;
            }
            __syncthreads();

            bf16x8 ak[2][2];
#pragma unroll
            for (int mt = 0; mt < 2; ++mt)
#pragma unroll
                for (int ks = 0; ks < 2; ++ks)
                    ak[mt][ks] = *(const bf16x8*)(&Ks[(mt * 16 + ln15) * 72 + ks * 32 + ln4 * 8]);

            floatx4 s[2][2];
#pragma unroll
            for (int mt = 0; mt < 2; ++mt)
#pragma unroll
                for (int nt = 0; nt < 2; ++nt) {
                    floatx4 acc = (floatx4){0.f, 0.f, 0.f, 0.f};
                    acc = __builtin_amdgcn_mfma_f32_16x16x32_bf16(ak[mt][0], qf[nt][0], acc, 0, 0, 0);
                    acc = __builtin_amdgcn_mfma_f32_16x16x32_bf16(ak[mt][1], qf[nt][1], acc, 0, 0, 0);
                    s[mt][nt] = acc;
                }

#pragma unroll
            for (int mt = 0; mt < 2; ++mt) {
                const int kp0 = kbase + mt * 16 + ln4 * 4;
#pragma unroll
                for (int rg = 0; rg < 4; ++rg) {
                    const int kpos = kp0 + rg;
                    const bool kin = (unsigned)kpos < (unsigned)S_LEN;
                    const float amv = kin ? amb[kpos] : 0.f;
#pragma unroll
                    for (int nt = 0; nt < 2; ++nt) {
                        const int qpos = q0 + nt * 16 + ln15;
                        const int dlt = kpos > qpos ? kpos - qpos : qpos - kpos;
                        const bool valid = glob || (kpos >= NGLB && kin && dlt <= WINSZ);
                        s[mt][nt][rg] = valid ? s[mt][nt][rg] + amv : NEGV;
                    }
                }
            }

            float alpha[2];
#pragma unroll
            for (int nt = 0; nt < 2; ++nt) {
                float mx = s[0][nt][0];
#pragma unroll
                for (int rg = 1; rg < 4; ++rg) mx = fmaxf(mx, s[0][nt][rg]);
#pragma unroll
                for (int rg = 0; rg < 4; ++rg) mx = fmaxf(mx, s[1][nt][rg]);
                mx = fmaxf(mx, __shfl_xor(mx, 16));
                mx = fmaxf(mx, __shfl_xor(mx, 32));
                const float mn = fmaxf(m_r[nt], mx);
                alpha[nt] = __expf(m_r[nt] - mn);
                m_r[nt] = mn;
            }

#pragma unroll
            for (int nt = 0; nt < 2; ++nt) {
                float sum = 0.f;
#pragma unroll
                for (int mt = 0; mt < 2; ++mt) {
                    ushort4 pk;
#pragma unroll
                    for (int rg = 0; rg < 4; ++rg) {
                        const float p = __expf(s[mt][nt][rg] - m_r[nt]);
                        sum += p;
                        ((unsigned short*)&pk)[rg] = f2bf(p);
                    }
                    *(ushort4*)(&Ps[wave * 1280 + (nt * 16 + ln15) * 40 + mt * 16 + ln4 * 4]) = pk;
                }
                sum += __shfl_xor(sum, 16);
                sum += __shfl_xor(sum, 32);
                l_r[nt] = l_r[nt] * alpha[nt] + sum;
            }

#pragma unroll
            for (int mt = 0; mt < 4; ++mt)
#pragma unroll
                for (int nt = 0; nt < 2; ++nt)
#pragma unroll
                    for (int rg = 0; rg < 4; ++rg) o[mt][nt][rg] *= alpha[nt];

            bf16x8 av[4], bp[2];
#pragma unroll
            for (int mt = 0; mt < 4; ++mt)
                av[mt] = *(const bf16x8*)(&Vs[(mt * 16 + ln15) * 40 + ln4 * 8]);
#pragma unroll
            for (int nt = 0; nt < 2; ++nt)
                bp[nt] = *(const bf16x8*)(&Ps[wave * 1280 + (nt * 16 + ln15) * 40 + ln4 * 8]);
#pragma unroll
            for (int mt = 0; mt < 4; ++mt)
#pragma unroll
                for (int nt = 0; nt < 2; ++nt)
                    o[mt][nt] = __builtin_amdgcn_mfma_f32_16x16x32_bf16(
                        av[mt], bp[nt], o[mt][nt], 0, 0, 0);
        }

        if (q0 >= NGLB) {
            const float inv0 = 1.f / l_r[0], inv1 = 1.f / l_r[1];
#pragma unroll
            for (int nt = 0; nt < 2; ++nt) {
                const float inv = nt ? inv1 : inv0;
                const long row = (long)b * S_LEN + q0 + nt * 16 + ln15;
#pragma unroll
                for (int mt = 0; mt < 4; ++mt) {
                    ushort4 ov;
#pragma unroll
                    for (int rg = 0; rg < 4; ++rg)
                        ((unsigned short*)&ov)[rg] = f2bf(o[mt][nt][rg] * inv);
                    *(ushort4*)(ctx + row * D_MODEL + h * DH + mt * 16 + ln4 * 4) = ov;
                }
            }
        }
    } else {
        // ---------------- global-query path (4 waves, 16 iters) ----------------
        unsigned short* Psg = (unsigned short*)smem;           // [4][32*72]
        float* Om   = (float*)(smem + 18432);                  // 64*36
        float* mW   = (float*)(smem + 27648);                  // [4][32]
        float* lW   = (float*)(smem + 28160);                  // [4][32]
        float* lTot = (float*)(smem + 28672);                  // [32]

        const int bh = blk;
        const int b = bh / NHEAD, h = bh % NHEAD;

        const unsigned short* kh  = k + (long)bh * S_LEN * DH;
        const unsigned short* vth = vt + (long)bh * DH * S_LEN;
        const float* amb = am + (long)b * S_LEN;

        bf16x8 qf[2][2];
#pragma unroll
        for (int nt = 0; nt < 2; ++nt)
#pragma unroll
            for (int ks = 0; ks < 2; ++ks)
                qf[nt][ks] = *(const bf16x8*)(q + ((long)bh * S_LEN + nt * 16 + ln15) * DH
                                              + ks * 32 + ln4 * 8);

        floatx4 o[4][2];
#pragma unroll
        for (int mt = 0; mt < 4; ++mt)
#pragma unroll
            for (int nt = 0; nt < 2; ++nt) o[mt][nt] = (floatx4){0.f, 0.f, 0.f, 0.f};
        float m_r[2] = {-1e30f, -1e30f}, l_r[2] = {0.f, 0.f};

        for (int it = 0; it < 16; ++it) {
            const int kbase = it * 256 + wave * 64;

            bf16x8 ak[4][2];
#pragma unroll
            for (int mt = 0; mt < 4; ++mt)
#pragma unroll
                for (int ks = 0; ks < 2; ++ks)
                    ak[mt][ks] = *(const bf16x8*)(kh + (long)(kbase + mt * 16 + ln15) * DH
                                                  + ks * 32 + ln4 * 8);

            floatx4 s[4][2];
#pragma unroll
            for (int mt = 0; mt < 4; ++mt)
#pragma unroll
                for (int nt = 0; nt < 2; ++nt) {
                    floatx4 acc = (floatx4){0.f, 0.f, 0.f, 0.f};
                    acc = __builtin_amdgcn_mfma_f32_16x16x32_bf16(ak[mt][0], qf[nt][0], acc, 0, 0, 0);
                    acc = __builtin_amdgcn_mfma_f32_16x16x32_bf16(ak[mt][1], qf[nt][1], acc, 0, 0, 0);
                    s[mt][nt] = acc;
                }

#pragma unroll
            for (int mt = 0; mt < 4; ++mt) {
                const int kp0 = kbase + mt * 16 + ln4 * 4;
#pragma unroll
                for (int rg = 0; rg < 4; ++rg) {
                    const float amv = amb[kp0 + rg];
#pragma unroll
                    for (int nt = 0; nt < 2; ++nt) s[mt][nt][rg] += amv;
                }
            }

            float alpha[2];
#pragma unroll
            for (int nt = 0; nt < 2; ++nt) {
                float mx = s[0][nt][0];
#pragma unroll
                for (int mt = 0; mt < 4; ++mt)
#pragma unroll
                    for (int rg = 0; rg < 4; ++rg) mx = fmaxf(mx, s[mt][nt][rg]);
                mx = fmaxf(mx, __shfl_xor(mx, 16));
                mx = fmaxf(mx, __shfl_xor(mx, 32));
                const float mn = fmaxf(m_r[nt], mx);
                alpha[nt] = __expf(m_r[nt] - mn);
                m_r[nt] = mn;
            }

#pragma unroll
            for (int nt = 0; nt < 2; ++nt) {
                float sum = 0.f;
#pragma unroll
                for (int mt = 0; mt < 4; ++mt) {
                    ushort4 pk;
#pragma unroll
                    for (int rg = 0; rg < 4; ++rg) {
                        const float p = __expf(s[mt][nt][rg] - m_r[nt]);
                        sum += p;
                        ((unsigned short*)&pk)[rg] = f2bf(p);
                    }
                    *(ushort4*)(&Psg[wave * 2304 + (nt * 16 + ln15) * 72 + mt * 16 + ln4 * 4]) = pk;
                }
                sum += __shfl_xor(sum, 16);
                sum += __shfl_xor(sum, 32);
                l_r[nt] = l_r[nt] * alpha[nt] + sum;
            }

#pragma unroll
            for (int mt = 0; mt < 4; ++mt)
#pragma unroll
                for (int nt = 0; nt < 2; ++nt)
#pragma unroll
                    for (int rg = 0; rg < 4; ++rg) o[mt][nt][rg] *= alpha[nt];

            bf16x8 av[4][2], bp[2][2];
#pragma unroll
            for (int mt = 0; mt < 4; ++mt)
#pragma unroll
                for (int ks = 0; ks < 2; ++ks)
                    av[mt][ks] = *(const bf16x8*)(vth + (long)(mt * 16 + ln15) * S_LEN
                                                  + kbase + ks * 32 + ln4 * 8);
#pragma unroll
            for (int nt = 0; nt < 2; ++nt)
#pragma unroll
                for (int ks = 0; ks < 2; ++ks)
                    bp[nt][ks] = *(const bf16x8*)(&Psg[wave * 2304 + (nt * 16 + ln15) * 72
                                                  + ks * 32 + ln4 * 8]);
#pragma unroll
            for (int mt = 0; mt < 4; ++mt)
#pragma unroll
                for (int nt = 0; nt < 2; ++nt) {
                    o[mt][nt] = __builtin_amdgcn_mfma_f32_16x16x32_bf16(
                        av[mt][0], bp[nt][0], o[mt][nt], 0, 0, 0);
                    o[mt][nt] = __builtin_amdgcn_mfma_f32_16x16x32_bf16(
                        av[mt][1], bp[nt][1], o[mt][nt], 0, 0, 0);
                }
        }

        if (ln4 == 0) {
#pragma unroll
            for (int nt = 0; nt < 2; ++nt) {
                mW[wave * 32 + nt * 16 + ln15] = m_r[nt];
                lW[wave * 32 + nt * 16 + ln15] = l_r[nt];
            }
        }
        for (int i = tid; i < 64 * 36; i += 256) Om[i] = 0.f;
        __syncthreads();

        float f[2];
#pragma unroll
        for (int nt = 0; nt < 2; ++nt) {
            const int qq = nt * 16 + ln15;
            float mt_ = mW[qq];
#pragma unroll
            for (int w = 1; w < 4; ++w) mt_ = fmaxf(mt_, mW[w * 32 + qq]);
            float lt = 0.f;
#pragma unroll
            for (int w = 0; w < 4; ++w) lt += __expf(mW[w * 32 + qq] - mt_) * lW[w * 32 + qq];
            f[nt] = __expf(m_r[nt] - mt_);
            if (wave == 0 && ln4 == 0) lTot[qq] = lt;
        }
#pragma unroll
        for (int mt = 0; mt < 4; ++mt)
#pragma unroll
            for (int nt = 0; nt < 2; ++nt)
#pragma unroll
                for (int rg = 0; rg < 4; ++rg) o[mt][nt][rg] *= f[nt];

        for (int wv = 0; wv < 4; ++wv) {
            if (wave == wv) {
#pragma unroll
                for (int mt = 0; mt < 4; ++mt)
#pragma unroll
                    for (int nt = 0; nt < 2; ++nt)
#pragma unroll
                        for (int rg = 0; rg < 4; ++rg)
                            Om[(mt * 16 + ln4 * 4 + rg) * 36 + nt * 16 + ln15] += o[mt][nt][rg];
            }
            __syncthreads();
        }

        const int qq = tid >> 3, d0 = (tid & 7) * 8;
        const float inv = 1.f / lTot[qq];
        ushort4 ov0, ov1;
#pragma unroll
        for (int i = 0; i < 4; ++i)
            ((unsigned short*)&ov0)[i] = f2bf(Om[(d0 + i) * 36 + qq] * inv);
#pragma unroll
        for (int i = 0; i < 4; ++i)
            ((unsigned short*)&ov1)[i] = f2bf(Om[(d0 + 4 + i) * 36 + qq] * inv);
        unsigned short* dst = ctx + ((long)b * S_LEN + qq) * D_MODEL + h * DH + d0;
        *(ushort4*)dst = ov0;
        *(ushort4*)(dst + 4) = ov1;
    }
}

// ---------------------------------------------------------------------------
// Fused split-K reduce + bias + residual + LayerNorm. x = p0+p1+bias+resid.
// One block per row (768 cols). Shfl wave-reduce (2 syncs, not 16).
// ---------------------------------------------------------------------------
__global__ __launch_bounds__(256) void ln2p_k(
    const float* __restrict__ p0, const float* __restrict__ p1,
    const float* __restrict__ bias, const float* __restrict__ resid,
    float* __restrict__ out, unsigned short* __restrict__ out_bf,
    const float* __restrict__ gw, const float* __restrict__ bw)
{
    __shared__ float red[8];
    const long base = (long)blockIdx.x * D_MODEL;
    const int t = threadIdx.x;
    const int wv = t >> 6, lane = t & 63;
    float v0 = p0[base + t]       + p1[base + t]       + bias[t]       + resid[base + t];
    float v1 = p0[base + t + 256] + p1[base + t + 256] + bias[t + 256] + resid[base + t + 256];
    float v2 = p0[base + t + 512] + p1[base + t + 512] + bias[t + 512] + resid[base + t + 512];

    float s = v0 + v1 + v2;
#pragma unroll
    for (int off = 32; off; off >>= 1) s += __shfl_xor(s, off);
    if (lane == 0) red[wv] = s;
    __syncthreads();
    const float mu = (red[0] + red[1] + red[2] + red[3]) * (1.f / 768.f);

    const float d0 = v0 - mu, d1 = v1 - mu, d2 = v2 - mu;
    float s2 = d0 * d0 + d1 * d1 + d2 * d2;
#pragma unroll
    for (int off = 32; off; off >>= 1) s2 += __shfl_xor(s2, off);
    if (lane == 0) red[4 + wv] = s2;
    __syncthreads();
    const float var = (red[4] + red[5] + red[6] + red[7]) * (1.f / 768.f);
    const float rs = rsqrtf(var + 1e-12f);

    const float y0 = d0 * rs * gw[t] + bw[t];
    const float y1 = d1 * rs * gw[t + 256] + bw[t + 256];
    const float y2 = d2 * rs * gw[t + 512] + bw[t + 512];
    if (out) {
        float* y = out + base;
        y[t] = y0; y[t + 256] = y1; y[t + 512] = y2;
    }
    if (out_bf) {
        unsigned short* yb = out_bf + base;
        yb[t] = f2bf(y0); yb[t + 256] = f2bf(y1); yb[t + 512] = f2bf(y2);
    }
}

// ---------------------------------------------------------------------------
extern "C" void kernel_launch(void* const* d_in, const int* in_sizes, int n_in,
                              void* d_out, int out_size, void* d_ws, size_t ws_size,
                              hipStream_t stream)
{
    const float* hid  = (const float*)d_in[0];
    const float* am   = (const float*)d_in[1];
    const float* Wq   = (const float*)d_in[2];
    const float* bq   = (const float*)d_in[3];
    const float* Wk   = (const float*)d_in[4];
    const float* bk   = (const float*)d_in[5];
    const float* Wv   = (const float*)d_in[6];
    const float* bv   = (const float*)d_in[7];
    const float* Wo   = (const float*)d_in[8];
    const float* bo   = (const float*)d_in[9];
    const float* ln1g = (const float*)d_in[10];
    const float* ln1b = (const float*)d_in[11];
    const float* Wi   = (const float*)d_in[12];
    const float* bi   = (const float*)d_in[13];
    const float* Wo2  = (const float*)d_in[14];
    const float* bo2  = (const float*)d_in[15];
    const float* ln2g = (const float*)d_in[16];
    const float* ln2b = (const float*)d_in[17];

    const long M  = (long)B_SZ * S_LEN;                 // 8192
    const long NQ = NQC;                                // 6291456

    unsigned short* W16 = (unsigned short*)d_ws;
    unsigned short* qb   = W16;             // bf16 (B,NH,S,DH) — q|k|v contiguous
    unsigned short* kb   = W16 + NQ;
    unsigned short* vb   = W16 + 2 * NQ;
    unsigned short* vtb  = W16 + 3 * NQ;    // bf16 (B,NH,DH,S)
    unsigned short* ctxb = W16 + 4 * NQ;    // bf16 (B,S,768)
    unsigned short* hidb = W16 + 5 * NQ;    // bf16 hidden
    unsigned short* wqt  = W16 + 6 * NQ;    // [Wq|Wk|Wv]^T contiguous 2304x768
    unsigned short* wkt  = wqt + 589824;
    unsigned short* wvt  = wkt + 589824;
    unsigned short* wot  = wvt + 589824;
    unsigned short* wit  = wot + 589824;    // 2359296
    unsigned short* wo2t = wit + 2359296;   // 2359296 -> ends at u16 44826624
    float* tmp   = (float*)(W16 + 44826624);  // attn_out fp32 -> ends u16 57409536
    float* partB1 = (float*)(W16 + 57409536); // Wo2 split slice1 -> ends u16 69992448
    float* bcat  = (float*)(W16 + 69992448);  // 2304 fp32
    // aliases over dead regions:
    float* partA0 = (float*)W16;                  // Wo slice0 (over qb,kb)
    float* partA1 = (float*)(W16 + 2 * NQ);       // Wo slice1 (over vb,vtb)
    unsigned short* interb = W16;                 // Wi out (over qb..vtb)
    unsigned short* attnb  = hidb;                // LN1 bf16 (over hidb)
    float* partB0 = (float*)(W16 + 4 * NQ);       // Wo2 slice0 (over ctxb,hidb)
    (void)ws_size; (void)in_sizes; (void)n_in; (void)out_size;

    // fused prep: 6 transposes (+0.125 fold into Wq) + bcat (+0.125 bq) + conv
    prep_k<<<dim3(13065), dim3(32, 8), 0, stream>>>(
        Wq, Wk, Wv, Wo, Wi, Wo2, wqt, wkt, wvt, wot, wit, wo2t,
        bq, bk, bv, bcat, hid, hidb);

    dim3 blk(256);

    // fused QKV: one GEMM, N = 2304, scatter to qb/kb/vb
    gemm_bf<2><<<dim3(1152), blk, 0, stream>>>(hidb, wqt, bcat, qb,
                                               M, 2304, 768, 18);

    vt_k<<<dim3(128, 24), blk, 0, stream>>>(vb, vtb);

    // fused band + global attention (glob blocks first for overlap)
    attn_k<<<dim3(792), blk, 0, stream>>>(qb, kb, vtb, am, ctxb);

    // Wo split-K x2 -> partA0/partA1 ; LN1 fuses reduce+bias+resid
    gemm_sp<<<dim3(768), blk, 0, stream>>>(ctxb, wot, partA0, partA1,
                                           M, 768, 384, 6, 384);
    ln2p_k<<<dim3(M), blk, 0, stream>>>(partA0, partA1, bo, hid,
                                        tmp, attnb, ln1g, ln1b);

    // inter = gelu(attn_out @ Wi + bi)
    gemm_bf<1><<<dim3(1536), blk, 0, stream>>>(attnb, wit, bi, interb,
                                               M, 3072, 768, 24);

    // Wo2 split-K x2 -> partB0/partB1 ; LN2 fuses reduce+bias+resid
    gemm_sp<<<dim3(768), blk, 0, stream>>>(interb, wo2t, partB0, partB1,
                                           M, 768, 1536, 6, 384);
    ln2p_k<<<dim3(M), blk, 0, stream>>>(partB0, partB1, bo2, tmp,
                                        (float*)d_out, nullptr, ln2g, ln2b);
}

// Round 3
// 411.866 us; speedup vs baseline: 1.1554x; 1.0246x over previous
//
#include <hip/hip_runtime.h>
#include <math.h>

#define NHEAD 12
#define DH 64
#define S_LEN 4096
#define B_SZ 2
#define D_MODEL 768
#define FF_DIM 3072
#define WINSZ 128
#define NGLB 32
#define NEGV -1e9f
#define NQC 6291456L

typedef __attribute__((ext_vector_type(8))) short bf16x8;
typedef __attribute__((ext_vector_type(4))) float floatx4;

__device__ __forceinline__ unsigned short f2bf(float x) {
    union { float f; unsigned u; } v; v.f = x;
    unsigned r = v.u + 0x7fffu + ((v.u >> 16) & 1u);
    return (unsigned short)(r >> 16);
}
__device__ __forceinline__ float bf2f(unsigned short x) {
    union { unsigned u; float f; } v; v.u = ((unsigned)x) << 16;
    return v.f;
}

__device__ __forceinline__ void async_copy16(const unsigned short* g, unsigned short* l) {
    __builtin_amdgcn_global_load_lds(
        (const __attribute__((address_space(1))) void*)g,
        (__attribute__((address_space(3))) void*)l, 16, 0, 0);
}

// ---------------------------------------------------------------------------
// Fused prep: 6 weight transposes (fp32 KxN -> bf16 NxK, Wq scaled 0.125)
// + bias concat (bq scaled 0.125) + hidden fp32->bf16 conversion.
// Block ranges: [0,6912) transposes, [6912,6921) bcat, [6921,13065) conv.
// ---------------------------------------------------------------------------
__global__ __launch_bounds__(256) void prep_k(
    const float* __restrict__ Wq, const float* __restrict__ Wk,
    const float* __restrict__ Wv, const float* __restrict__ Wo,
    const float* __restrict__ Wi, const float* __restrict__ Wo2,
    unsigned short* __restrict__ wqt, unsigned short* __restrict__ wkt,
    unsigned short* __restrict__ wvt, unsigned short* __restrict__ wot,
    unsigned short* __restrict__ wit, unsigned short* __restrict__ wo2t,
    const float* __restrict__ bq, const float* __restrict__ bk,
    const float* __restrict__ bv, float* __restrict__ bcat,
    const float* __restrict__ hid, unsigned short* __restrict__ hidb)
{
    __shared__ float tile[32][33];
    const int bid = blockIdx.x;
    const int tx = threadIdx.x, ty = threadIdx.y;

    if (bid < 6912) {
        const float* src; unsigned short* dst; int K, N, nx, local; float scale = 1.f;
        if (bid < 576)       { src = Wq;  dst = wqt;  K = 768;  N = 768;  nx = 24; local = bid;        scale = 0.125f; }
        else if (bid < 1152) { src = Wk;  dst = wkt;  K = 768;  N = 768;  nx = 24; local = bid - 576;  }
        else if (bid < 1728) { src = Wv;  dst = wvt;  K = 768;  N = 768;  nx = 24; local = bid - 1152; }
        else if (bid < 2304) { src = Wo;  dst = wot;  K = 768;  N = 768;  nx = 24; local = bid - 1728; }
        else if (bid < 4608) { src = Wi;  dst = wit;  K = 768;  N = 3072; nx = 96; local = bid - 2304; }
        else                 { src = Wo2; dst = wo2t; K = 3072; N = 768;  nx = 24; local = bid - 4608; }
        const int n0 = (local % nx) * 32, k0 = (local / nx) * 32;
#pragma unroll
        for (int i = 0; i < 4; ++i)
            tile[ty + 8 * i][tx] = src[(long)(k0 + ty + 8 * i) * N + n0 + tx];
        __syncthreads();
#pragma unroll
        for (int i = 0; i < 4; ++i)
            dst[(long)(n0 + ty + 8 * i) * K + k0 + tx] = f2bf(tile[tx][ty + 8 * i] * scale);
    } else if (bid < 6921) {
        const int t = ty * 32 + tx;
        const int i = (bid - 6912) * 256 + t;
        if (i < 768) bcat[i] = bq[i] * 0.125f;
        else if (i < 1536) bcat[i] = bk[i - 768];
        else if (i < 2304) bcat[i] = bv[i - 1536];
    } else {
        const int t = ty * 32 + tx;
        const long i = ((long)(bid - 6921) * 256 + t) * 4;
        float4 v = *(const float4*)(hid + i);
        ushort4 o;
        o.x = f2bf(v.x); o.y = f2bf(v.y); o.z = f2bf(v.z); o.w = f2bf(v.w);
        *(ushort4*)(hidb + i) = o;
    }
}

// ---------------------------------------------------------------------------
// V (B,NH,S,DH) bf16 -> Vt (B,NH,DH,S) bf16
// ---------------------------------------------------------------------------
__global__ __launch_bounds__(256) void vt_k(
    const unsigned short* __restrict__ v, unsigned short* __restrict__ vt)
{
    const int bh = blockIdx.y;
    const int s0 = blockIdx.x * 32;
    const int w = threadIdx.x >> 6, lane = threadIdx.x & 63;
    const unsigned short* src = v + ((long)bh * S_LEN + s0 + w * 8) * DH + lane;
    unsigned short r[8];
#pragma unroll
    for (int j = 0; j < 8; ++j) r[j] = src[j * DH];
    unsigned short* dst = vt + ((long)bh * DH + lane) * S_LEN + s0 + w * 8;
    ushort4 lo, hi;
    lo.x = r[0]; lo.y = r[1]; lo.z = r[2]; lo.w = r[3];
    hi.x = r[4]; hi.y = r[5]; hi.z = r[6]; hi.w = r[7];
    *(ushort4*)dst = lo;
    *(ushort4*)(dst + 4) = hi;
}

// ---------------------------------------------------------------------------
// bf16 MFMA GEMM, double-buffered minimum-2-phase pipeline (T3-min):
// per iter {STAGE(buf^1, t+1) -> ds_read+MFMA on buf -> one __syncthreads}.
// The barrier's implicit vmcnt(0)+lgkmcnt(0) drain is the only sync; staging
// latency hides under the current tile's compute. LDS 2x16 KiB.
// EPI 1: gelu -> bf16
// EPI 2: fused QKV scatter: part=n/768 (q|k|v) -> bf16 (Q scale pre-folded)
// ---------------------------------------------------------------------------
template <int EPI>
__global__ __launch_bounds__(256) void gemm_bf(
    const unsigned short* __restrict__ A, const unsigned short* __restrict__ BT,
    const float* __restrict__ bias, void* __restrict__ out,
    int M, int N, int K, int nx)
{
    __shared__ unsigned short As[2][128 * 32];
    __shared__ unsigned short Bs[2][128 * 32];
    const int tid = threadIdx.x;
    const int wave = tid >> 6, lane = tid & 63;
    const int t8 = (blockIdx.x & 7) * (gridDim.x >> 3) + (blockIdx.x >> 3);
    const int m0 = (t8 / nx) * 128, n0 = (t8 % nx) * 128;
    const int wr = (wave >> 1) * 64, wc = (wave & 1) * 64;

    floatx4 acc[4][4];
#pragma unroll
    for (int i = 0; i < 4; ++i)
#pragma unroll
        for (int j = 0; j < 4; ++j) acc[i][j] = (floatx4){0.f, 0.f, 0.f, 0.f};

    const int srow = lane >> 2;
    const int schk = (((lane & 3) ^ (srow & 3))) * 8;   // XOR-swizzled stage
    const int r = lane & 15;
    const int q8 = ((lane >> 4) ^ (lane & 3)) * 8;      // XOR-swizzled read

    const int NT = K >> 5;
    const unsigned short* aSrc0 = A  + (long)(m0 + wave * 32 + srow) * K + schk;
    const unsigned short* aSrc1 = A  + (long)(m0 + wave * 32 + 16 + srow) * K + schk;
    const unsigned short* bSrc0 = BT + (long)(n0 + wave * 32 + srow) * K + schk;
    const unsigned short* bSrc1 = BT + (long)(n0 + wave * 32 + 16 + srow) * K + schk;
    const int g0 = wave * 1024, g1 = wave * 1024 + 512;

    // prologue: stage tile 0
    async_copy16(aSrc0, &As[0][g0]);
    async_copy16(bSrc0, &Bs[0][g0]);
    async_copy16(aSrc1, &As[0][g1]);
    async_copy16(bSrc1, &Bs[0][g1]);
    __syncthreads();

    for (int t = 0; t < NT; ++t) {
        const int cur = t & 1;
        if (t + 1 < NT) {
            const int k0 = (t + 1) << 5;
            async_copy16(aSrc0 + k0, &As[cur ^ 1][g0]);
            async_copy16(bSrc0 + k0, &Bs[cur ^ 1][g0]);
            async_copy16(aSrc1 + k0, &As[cur ^ 1][g1]);
            async_copy16(bSrc1 + k0, &Bs[cur ^ 1][g1]);
        }
        __builtin_amdgcn_sched_barrier(0);

        bf16x8 af[4], bfr[4];
#pragma unroll
        for (int i = 0; i < 4; ++i) {
            af[i]  = *(const bf16x8*)&As[cur][(wr + i * 16 + r) * 32 + q8];
            bfr[i] = *(const bf16x8*)&Bs[cur][(wc + i * 16 + r) * 32 + q8];
        }
        __builtin_amdgcn_s_setprio(1);
#pragma unroll
        for (int i = 0; i < 4; ++i)
#pragma unroll
            for (int j = 0; j < 4; ++j)
                acc[i][j] = __builtin_amdgcn_mfma_f32_16x16x32_bf16(
                    af[i], bfr[j], acc[i][j], 0, 0, 0);
        __builtin_amdgcn_s_setprio(0);
        __syncthreads();
    }

    const int col_l = lane & 15, row_l = (lane >> 4) * 4;
#pragma unroll
    for (int i = 0; i < 4; ++i) {
#pragma unroll
        for (int j = 0; j < 4; ++j) {
            const int n = n0 + wc + j * 16 + col_l;
            const float bv = bias[n];
#pragma unroll
            for (int rg = 0; rg < 4; ++rg) {
                const int m = m0 + wr + i * 16 + row_l + rg;
                float v = acc[i][j][rg] + bv;
                if (EPI == 1) {
                    v = 0.5f * v * (1.f + erff(v * 0.70710678118654752f));
                    ((unsigned short*)out)[(long)m * N + n] = f2bf(v);
                } else {
                    const int bb = m >> 12, s = m & 4095;
                    const int part = n / 768;          // 0=q, 1=k, 2=v
                    const int nn = n - part * 768;
                    const int hh = nn >> 6, dh = nn & 63;
                    ((unsigned short*)out)[(long)part * NQC +
                        (((long)bb * NHEAD + hh) * S_LEN + s) * DH + dh] = f2bf(v);
                }
            }
        }
    }
}

// ---------------------------------------------------------------------------
// Split-K (x2) bf16 MFMA GEMM, same double-buffered pipeline. Raw fp32
// partials; reduction happens inside ln2p_k.
// ---------------------------------------------------------------------------
__global__ __launch_bounds__(256) void gemm_sp(
    const unsigned short* __restrict__ A, const unsigned short* __restrict__ BT,
    float* __restrict__ p0, float* __restrict__ p1,
    int M, int N, int K2, int nx, int ntile)
{
    __shared__ unsigned short As[2][128 * 32];
    __shared__ unsigned short Bs[2][128 * 32];
    const int tid = threadIdx.x;
    const int wave = tid >> 6, lane = tid & 63;
    const int t8 = (blockIdx.x & 7) * (gridDim.x >> 3) + (blockIdx.x >> 3);
    const int slice = t8 >= ntile;
    const int tile = t8 - slice * ntile;
    const int m0 = (tile / nx) * 128, n0 = (tile % nx) * 128;
    const int kbeg = slice * K2;
    float* P = slice ? p1 : p0;
    const int wr = (wave >> 1) * 64, wc = (wave & 1) * 64;

    floatx4 acc[4][4];
#pragma unroll
    for (int i = 0; i < 4; ++i)
#pragma unroll
        for (int j = 0; j < 4; ++j) acc[i][j] = (floatx4){0.f, 0.f, 0.f, 0.f};

    const int srow = lane >> 2;
    const int schk = (((lane & 3) ^ (srow & 3))) * 8;
    const int r = lane & 15;
    const int q8 = ((lane >> 4) ^ (lane & 3)) * 8;
    const long Kl = (long)K2 * 2;

    const int NT = K2 >> 5;
    const unsigned short* aSrc0 = A  + (long)(m0 + wave * 32 + srow) * Kl + kbeg + schk;
    const unsigned short* aSrc1 = A  + (long)(m0 + wave * 32 + 16 + srow) * Kl + kbeg + schk;
    const unsigned short* bSrc0 = BT + (long)(n0 + wave * 32 + srow) * Kl + kbeg + schk;
    const unsigned short* bSrc1 = BT + (long)(n0 + wave * 32 + 16 + srow) * Kl + kbeg + schk;
    const int g0 = wave * 1024, g1 = wave * 1024 + 512;

    async_copy16(aSrc0, &As[0][g0]);
    async_copy16(bSrc0, &Bs[0][g0]);
    async_copy16(aSrc1, &As[0][g1]);
    async_copy16(bSrc1, &Bs[0][g1]);
    __syncthreads();

    for (int t = 0; t < NT; ++t) {
        const int cur = t & 1;
        if (t + 1 < NT) {
            const int k0 = (t + 1) << 5;
            async_copy16(aSrc0 + k0, &As[cur ^ 1][g0]);
            async_copy16(bSrc0 + k0, &Bs[cur ^ 1][g0]);
            async_copy16(aSrc1 + k0, &As[cur ^ 1][g1]);
            async_copy16(bSrc1 + k0, &Bs[cur ^ 1][g1]);
        }
        __builtin_amdgcn_sched_barrier(0);

        bf16x8 af[4], bfr[4];
#pragma unroll
        for (int i = 0; i < 4; ++i) {
            af[i]  = *(const bf16x8*)&As[cur][(wr + i * 16 + r) * 32 + q8];
            bfr[i] = *(const bf16x8*)&Bs[cur][(wc + i * 16 + r) * 32 + q8];
        }
        __builtin_amdgcn_s_setprio(1);
#pragma unroll
        for (int i = 0; i < 4; ++i)
#pragma unroll
            for (int j = 0; j < 4; ++j)
                acc[i][j] = __builtin_amdgcn_mfma_f32_16x16x32_bf16(
                    af[i], bfr[j], acc[i][j], 0, 0, 0);
        __builtin_amdgcn_s_setprio(0);
        __syncthreads();
    }

    const int col_l = lane & 15, row_l = (lane >> 4) * 4;
#pragma unroll
    for (int i = 0; i < 4; ++i)
#pragma unroll
        for (int j = 0; j < 4; ++j) {
            const int n = n0 + wc + j * 16 + col_l;
#pragma unroll
            for (int rg = 0; rg < 4; ++rg) {
                const int m = m0 + wr + i * 16 + row_l + rg;
                P[(long)m * N + n] = acc[i][j][rg];
            }
        }
}

// ---------------------------------------------------------------------------
// Fused attention: blocks [0,24) = global-query path (4 waves, 16 iters),
// blocks [24,792) = band path (b,h,chunk; 4 waves x 32 queries).
// Glob blocks launch FIRST so they overlap the band wave-front.
// Band suppresses stores for q0 < NGLB (those rows belong to glob) -> no race.
// ---------------------------------------------------------------------------
__global__ __launch_bounds__(256) void attn_k(
    const unsigned short* __restrict__ q, const unsigned short* __restrict__ k,
    const unsigned short* __restrict__ vt, const float* __restrict__ am,
    unsigned short* __restrict__ ctx)
{
    __shared__ __align__(16) unsigned char smem[28800];
    const int blk = blockIdx.x;
    const int tid = threadIdx.x;
    const int wave = tid >> 6, lane = tid & 63;
    const int ln15 = lane & 15, ln4 = lane >> 4;

    if (blk >= 24) {
        // ---------------- band path ----------------
        unsigned short* Ks = (unsigned short*)smem;            // 32*72
        unsigned short* Vs = Ks + 32 * 72;                     // 64*40
        unsigned short* Ps = Vs + 64 * 40;                     // [4][32*40]

        const int bb = blk - 24;
        const int c = bb & 31;
        const int h = (bb >> 5) % NHEAD;
        const int b = bb / (32 * NHEAD);
        const long bh = (long)b * NHEAD + h;

        const unsigned short* kh  = k + bh * S_LEN * DH;
        const unsigned short* vth = vt + bh * (long)DH * S_LEN;
        const float* amb = am + (long)b * S_LEN;

        const int q0 = c * WINSZ + wave * 32;

        bf16x8 qf[2][2];
#pragma unroll
        for (int nt = 0; nt < 2; ++nt)
#pragma unroll
            for (int ks = 0; ks < 2; ++ks)
                qf[nt][ks] = *(const bf16x8*)(q + (bh * S_LEN + q0 + nt * 16 + ln15) * DH
                                              + ks * 32 + ln4 * 8);

        floatx4 o[4][2];
#pragma unroll
        for (int mt = 0; mt < 4; ++mt)
#pragma unroll
            for (int nt = 0; nt < 2; ++nt) o[mt][nt] = (floatx4){0.f, 0.f, 0.f, 0.f};
        float m_r[2] = {-1e30f, -1e30f}, l_r[2] = {0.f, 0.f};

        const int sk_key = tid >> 3, sk_ch = tid & 7;
        const int sv_dim = tid & 63, sv_ch = tid >> 6;
        const bf16x8 zero8 = {0, 0, 0, 0, 0, 0, 0, 0};

        for (int tile = 0; tile < 13; ++tile) {
            const bool glob = (tile == 12);
            const int kbase = glob ? 0 : (c * WINSZ - WINSZ + tile * 32);

            __syncthreads();
            {
                int kpos = kbase + sk_key;
                bf16x8 val = zero8;
                if ((unsigned)kpos < (unsigned)S_LEN)
                    val = *(const bf16x8*)(kh + (long)kpos * DH + sk_ch * 8);
                *(bf16x8*)(&Ks[sk_key * 72 + sk_ch * 8]) = val;
            }
            {
                int kc = kbase + sv_ch * 8;
                bf16x8 val = zero8;
                if (kc >= 0 && kc + 8 <= S_LEN)
                    val = *(const bf16x8*)(vth + (long)sv_dim * S_LEN + kc);
                *(bf16x8*)(&Vs[sv_dim * 40 + sv_ch * 8]) = val;
            }
            __syncthreads();

            bf16x8 ak[2][2];
#pragma unroll
            for (int mt = 0; mt < 2; ++mt)
#pragma unroll
                for (int ks = 0; ks < 2; ++ks)
                    ak[mt][ks] = *(const bf16x8*)(&Ks[(mt * 16 + ln15) * 72 + ks * 32 + ln4 * 8]);

            floatx4 s[2][2];
#pragma unroll
            for (int mt = 0; mt < 2; ++mt)
#pragma unroll
                for (int nt = 0; nt < 2; ++nt) {
                    floatx4 acc = (floatx4){0.f, 0.f, 0.f, 0.f};
                    acc = __builtin_amdgcn_mfma_f32_16x16x32_bf16(ak[mt][0], qf[nt][0], acc, 0, 0, 0);
                    acc = __builtin_amdgcn_mfma_f32_16x16x32_bf16(ak[mt][1], qf[nt][1], acc, 0, 0, 0);
                    s[mt][nt] = acc;
                }

#pragma unroll
            for (int mt = 0; mt < 2; ++mt) {
                const int kp0 = kbase + mt * 16 + ln4 * 4;
#pragma unroll
                for (int rg = 0; rg < 4; ++rg) {
                    const int kpos = kp0 + rg;
                    const bool kin = (unsigned)kpos < (unsigned)S_LEN;
                    const float amv = kin ? amb[kpos] : 0.f;
#pragma unroll
                    for (int nt = 0; nt < 2; ++nt) {
                        const int qpos = q0 + nt * 16 + ln15;
                        const int dlt = kpos > qpos ? kpos - qpos : qpos - kpos;
                        const bool valid = glob || (kpos >= NGLB && kin && dlt <= WINSZ);
                        s[mt][nt][rg] = valid ? s[mt][nt][rg] + amv : NEGV;
                    }
                }
            }

            float alpha[2];
#pragma unroll
            for (int nt = 0; nt < 2; ++nt) {
                float mx = s[0][nt][0];
#pragma unroll
                for (int rg = 1; rg < 4; ++rg) mx = fmaxf(mx, s[0][nt][rg]);
#pragma unroll
                for (int rg = 0; rg < 4; ++rg) mx = fmaxf(mx, s[1][nt][rg]);
                mx = fmaxf(mx, __shfl_xor(mx, 16));
                mx = fmaxf(mx, __shfl_xor(mx, 32));
                const float mn = fmaxf(m_r[nt], mx);
                alpha[nt] = __expf(m_r[nt] - mn);
                m_r[nt] = mn;
            }

#pragma unroll
            for (int nt = 0; nt < 2; ++nt) {
                float sum = 0.f;
#pragma unroll
                for (int mt = 0; mt < 2; ++mt) {
                    ushort4 pk;
#pragma unroll
                    for (int rg = 0; rg < 4; ++rg) {
                        const float p = __expf(s[mt][nt][rg] - m_r[nt]);
                        sum += p;
                        ((unsigned short*)&pk)[rg] = f2bf(p);
                    }
                    *(ushort4*)(&Ps[wave * 1280 + (nt * 16 + ln15) * 40 + mt * 16 + ln4 * 4]) = pk;
                }
                sum += __shfl_xor(sum, 16);
                sum += __shfl_xor(sum, 32);
                l_r[nt] = l_r[nt] * alpha[nt] + sum;
            }

#pragma unroll
            for (int mt = 0; mt < 4; ++mt)
#pragma unroll
                for (int nt = 0; nt < 2; ++nt)
#pragma unroll
                    for (int rg = 0; rg < 4; ++rg) o[mt][nt][rg] *= alpha[nt];

            bf16x8 av[4], bp[2];
#pragma unroll
            for (int mt = 0; mt < 4; ++mt)
                av[mt] = *(const bf16x8*)(&Vs[(mt * 16 + ln15) * 40 + ln4 * 8]);
#pragma unroll
            for (int nt = 0; nt < 2; ++nt)
                bp[nt] = *(const bf16x8*)(&Ps[wave * 1280 + (nt * 16 + ln15) * 40 + ln4 * 8]);
#pragma unroll
            for (int mt = 0; mt < 4; ++mt)
#pragma unroll
                for (int nt = 0; nt < 2; ++nt)
                    o[mt][nt] = __builtin_amdgcn_mfma_f32_16x16x32_bf16(
                        av[mt], bp[nt], o[mt][nt], 0, 0, 0);
        }

        if (q0 >= NGLB) {
            const float inv0 = 1.f / l_r[0], inv1 = 1.f / l_r[1];
#pragma unroll
            for (int nt = 0; nt < 2; ++nt) {
                const float inv = nt ? inv1 : inv0;
                const long row = (long)b * S_LEN + q0 + nt * 16 + ln15;
#pragma unroll
                for (int mt = 0; mt < 4; ++mt) {
                    ushort4 ov;
#pragma unroll
                    for (int rg = 0; rg < 4; ++rg)
                        ((unsigned short*)&ov)[rg] = f2bf(o[mt][nt][rg] * inv);
                    *(ushort4*)(ctx + row * D_MODEL + h * DH + mt * 16 + ln4 * 4) = ov;
                }
            }
        }
    } else {
        // ---------------- global-query path (4 waves, 16 iters) ----------------
        unsigned short* Psg = (unsigned short*)smem;           // [4][32*72]
        float* Om   = (float*)(smem + 18432);                  // 64*36
        float* mW   = (float*)(smem + 27648);                  // [4][32]
        float* lW   = (float*)(smem + 28160);                  // [4][32]
        float* lTot = (float*)(smem + 28672);                  // [32]

        const int bh = blk;
        const int b = bh / NHEAD, h = bh % NHEAD;

        const unsigned short* kh  = k + (long)bh * S_LEN * DH;
        const unsigned short* vth = vt + (long)bh * DH * S_LEN;
        const float* amb = am + (long)b * S_LEN;

        bf16x8 qf[2][2];
#pragma unroll
        for (int nt = 0; nt < 2; ++nt)
#pragma unroll
            for (int ks = 0; ks < 2; ++ks)
                qf[nt][ks] = *(const bf16x8*)(q + ((long)bh * S_LEN + nt * 16 + ln15) * DH
                                              + ks * 32 + ln4 * 8);

        floatx4 o[4][2];
#pragma unroll
        for (int mt = 0; mt < 4; ++mt)
#pragma unroll
            for (int nt = 0; nt < 2; ++nt) o[mt][nt] = (floatx4){0.f, 0.f, 0.f, 0.f};
        float m_r[2] = {-1e30f, -1e30f}, l_r[2] = {0.f, 0.f};

        for (int it = 0; it < 16; ++it) {
            const int kbase = it * 256 + wave * 64;

            bf16x8 ak[4][2];
#pragma unroll
            for (int mt = 0; mt < 4; ++mt)
#pragma unroll
                for (int ks = 0; ks < 2; ++ks)
                    ak[mt][ks] = *(const bf16x8*)(kh + (long)(kbase + mt * 16 + ln15) * DH
                                                  + ks * 32 + ln4 * 8);

            floatx4 s[4][2];
#pragma unroll
            for (int mt = 0; mt < 4; ++mt)
#pragma unroll
                for (int nt = 0; nt < 2; ++nt) {
                    floatx4 acc = (floatx4){0.f, 0.f, 0.f, 0.f};
                    acc = __builtin_amdgcn_mfma_f32_16x16x32_bf16(ak[mt][0], qf[nt][0], acc, 0, 0, 0);
                    acc = __builtin_amdgcn_mfma_f32_16x16x32_bf16(ak[mt][1], qf[nt][1], acc, 0, 0, 0);
                    s[mt][nt] = acc;
                }

#pragma unroll
            for (int mt = 0; mt < 4; ++mt) {
                const int kp0 = kbase + mt * 16 + ln4 * 4;
#pragma unroll
                for (int rg = 0; rg < 4; ++rg) {
                    const float amv = amb[kp0 + rg];
#pragma unroll
                    for (int nt = 0; nt < 2; ++nt) s[mt][nt][rg] += amv;
                }
            }

            float alpha[2];
#pragma unroll
            for (int nt = 0; nt < 2; ++nt) {
                float mx = s[0][nt][0];
#pragma unroll
                for (int mt = 0; mt < 4; ++mt)
#pragma unroll
                    for (int rg = 0; rg < 4; ++rg) mx = fmaxf(mx, s[mt][nt][rg]);
                mx = fmaxf(mx, __shfl_xor(mx, 16));
                mx = fmaxf(mx, __shfl_xor(mx, 32));
                const float mn = fmaxf(m_r[nt], mx);
                alpha[nt] = __expf(m_r[nt] - mn);
                m_r[nt] = mn;
            }

#pragma unroll
            for (int nt = 0; nt < 2; ++nt) {
                float sum = 0.f;
#pragma unroll
                for (int mt = 0; mt < 4; ++mt) {
                    ushort4 pk;
#pragma unroll
                    for (int rg = 0; rg < 4; ++rg) {
                        const float p = __expf(s[mt][nt][rg] - m_r[nt]);
                        sum += p;
                        ((unsigned short*)&pk)[rg] = f2bf(p);
                    }
                    *(ushort4*)(&Psg[wave * 2304 + (nt * 16 + ln15) * 72 + mt * 16 + ln4 * 4]) = pk;
                }
                sum += __shfl_xor(sum, 16);
                sum += __shfl_xor(sum, 32);
                l_r[nt] = l_r[nt] * alpha[nt] + sum;
            }

#pragma unroll
            for (int mt = 0; mt < 4; ++mt)
#pragma unroll
                for (int nt = 0; nt < 2; ++nt)
#pragma unroll
                    for (int rg = 0; rg < 4; ++rg) o[mt][nt][rg] *= alpha[nt];

            bf16x8 av[4][2], bp[2][2];
#pragma unroll
            for (int mt = 0; mt < 4; ++mt)
#pragma unroll
                for (int ks = 0; ks < 2; ++ks)
                    av[mt][ks] = *(const bf16x8*)(vth + (long)(mt * 16 + ln15) * S_LEN
                                                  + kbase + ks * 32 + ln4 * 8);
#pragma unroll
            for (int nt = 0; nt < 2; ++nt)
#pragma unroll
                for (int ks = 0; ks < 2; ++ks)
                    bp[nt][ks] = *(const bf16x8*)(&Psg[wave * 2304 + (nt * 16 + ln15) * 72
                                                  + ks * 32 + ln4 * 8]);
#pragma unroll
            for (int mt = 0; mt < 4; ++mt)
#pragma unroll
                for (int nt = 0; nt < 2; ++nt) {
                    o[mt][nt] = __builtin_amdgcn_mfma_f32_16x16x32_bf16(
                        av[mt][0], bp[nt][0], o[mt][nt], 0, 0, 0);
                    o[mt][nt] = __builtin_amdgcn_mfma_f32_16x16x32_bf16(
                        av[mt][1], bp[nt][1], o[mt][nt], 0, 0, 0);
                }
        }

        if (ln4 == 0) {
#pragma unroll
            for (int nt = 0; nt < 2; ++nt) {
                mW[wave * 32 + nt * 16 + ln15] = m_r[nt];
                lW[wave * 32 + nt * 16 + ln15] = l_r[nt];
            }
        }
        for (int i = tid; i < 64 * 36; i += 256) Om[i] = 0.f;
        __syncthreads();

        float f[2];
#pragma unroll
        for (int nt = 0; nt < 2; ++nt) {
            const int qq = nt * 16 + ln15;
            float mt_ = mW[qq];
#pragma unroll
            for (int w = 1; w < 4; ++w) mt_ = fmaxf(mt_, mW[w * 32 + qq]);
            float lt = 0.f;
#pragma unroll
            for (int w = 0; w < 4; ++w) lt += __expf(mW[w * 32 + qq] - mt_) * lW[w * 32 + qq];
            f[nt] = __expf(m_r[nt] - mt_);
            if (wave == 0 && ln4 == 0) lTot[qq] = lt;
        }
#pragma unroll
        for (int mt = 0; mt < 4; ++mt)
#pragma unroll
            for (int nt = 0; nt < 2; ++nt)
#pragma unroll
                for (int rg = 0; rg < 4; ++rg) o[mt][nt][rg] *= f[nt];

        for (int wv = 0; wv < 4; ++wv) {
            if (wave == wv) {
#pragma unroll
                for (int mt = 0; mt < 4; ++mt)
#pragma unroll
                    for (int nt = 0; nt < 2; ++nt)
#pragma unroll
                        for (int rg = 0; rg < 4; ++rg)
                            Om[(mt * 16 + ln4 * 4 + rg) * 36 + nt * 16 + ln15] += o[mt][nt][rg];
            }
            __syncthreads();
        }

        const int qq = tid >> 3, d0 = (tid & 7) * 8;
        const float inv = 1.f / lTot[qq];
        ushort4 ov0, ov1;
#pragma unroll
        for (int i = 0; i < 4; ++i)
            ((unsigned short*)&ov0)[i] = f2bf(Om[(d0 + i) * 36 + qq] * inv);
#pragma unroll
        for (int i = 0; i < 4; ++i)
            ((unsigned short*)&ov1)[i] = f2bf(Om[(d0 + 4 + i) * 36 + qq] * inv);
        unsigned short* dst = ctx + ((long)b * S_LEN + qq) * D_MODEL + h * DH + d0;
        *(ushort4*)dst = ov0;
        *(ushort4*)(dst + 4) = ov1;
    }
}

// ---------------------------------------------------------------------------
// Fused split-K reduce + bias + residual + LayerNorm. x = p0+p1+bias+resid.
// One block per row (768 cols). Shfl wave-reduce (2 syncs, not 16).
// ---------------------------------------------------------------------------
__global__ __launch_bounds__(256) void ln2p_k(
    const float* __restrict__ p0, const float* __restrict__ p1,
    const float* __restrict__ bias, const float* __restrict__ resid,
    float* __restrict__ out, unsigned short* __restrict__ out_bf,
    const float* __restrict__ gw, const float* __restrict__ bw)
{
    __shared__ float red[8];
    const long base = (long)blockIdx.x * D_MODEL;
    const int t = threadIdx.x;
    const int wv = t >> 6, lane = t & 63;
    float v0 = p0[base + t]       + p1[base + t]       + bias[t]       + resid[base + t];
    float v1 = p0[base + t + 256] + p1[base + t + 256] + bias[t + 256] + resid[base + t + 256];
    float v2 = p0[base + t + 512] + p1[base + t + 512] + bias[t + 512] + resid[base + t + 512];

    float s = v0 + v1 + v2;
#pragma unroll
    for (int off = 32; off; off >>= 1) s += __shfl_xor(s, off);
    if (lane == 0) red[wv] = s;
    __syncthreads();
    const float mu = (red[0] + red[1] + red[2] + red[3]) * (1.f / 768.f);

    const float d0 = v0 - mu, d1 = v1 - mu, d2 = v2 - mu;
    float s2 = d0 * d0 + d1 * d1 + d2 * d2;
#pragma unroll
    for (int off = 32; off; off >>= 1) s2 += __shfl_xor(s2, off);
    if (lane == 0) red[4 + wv] = s2;
    __syncthreads();
    const float var = (red[4] + red[5] + red[6] + red[7]) * (1.f / 768.f);
    const float rs = rsqrtf(var + 1e-12f);

    const float y0 = d0 * rs * gw[t] + bw[t];
    const float y1 = d1 * rs * gw[t + 256] + bw[t + 256];
    const float y2 = d2 * rs * gw[t + 512] + bw[t + 512];
    if (out) {
        float* y = out + base;
        y[t] = y0; y[t + 256] = y1; y[t + 512] = y2;
    }
    if (out_bf) {
        unsigned short* yb = out_bf + base;
        yb[t] = f2bf(y0); yb[t + 256] = f2bf(y1); yb[t + 512] = f2bf(y2);
    }
}

// ---------------------------------------------------------------------------
extern "C" void kernel_launch(void* const* d_in, const int* in_sizes, int n_in,
                              void* d_out, int out_size, void* d_ws, size_t ws_size,
                              hipStream_t stream)
{
    const float* hid  = (const float*)d_in[0];
    const float* am   = (const float*)d_in[1];
    const float* Wq   = (const float*)d_in[2];
    const float* bq   = (const float*)d_in[3];
    const float* Wk   = (const float*)d_in[4];
    const float* bk   = (const float*)d_in[5];
    const float* Wv   = (const float*)d_in[6];
    const float* bv   = (const float*)d_in[7];
    const float* Wo   = (const float*)d_in[8];
    const float* bo   = (const float*)d_in[9];
    const float* ln1g = (const float*)d_in[10];
    const float* ln1b = (const float*)d_in[11];
    const float* Wi   = (const float*)d_in[12];
    const float* bi   = (const float*)d_in[13];
    const float* Wo2  = (const float*)d_in[14];
    const float* bo2  = (const float*)d_in[15];
    const float* ln2g = (const float*)d_in[16];
    const float* ln2b = (const float*)d_in[17];

    const long M  = (long)B_SZ * S_LEN;                 // 8192
    const long NQ = NQC;                                // 6291456

    unsigned short* W16 = (unsigned short*)d_ws;
    unsigned short* qb   = W16;             // bf16 (B,NH,S,DH) — q|k|v contiguous
    unsigned short* kb   = W16 + NQ;
    unsigned short* vb   = W16 + 2 * NQ;
    unsigned short* vtb  = W16 + 3 * NQ;    // bf16 (B,NH,DH,S)
    unsigned short* ctxb = W16 + 4 * NQ;    // bf16 (B,S,768)
    unsigned short* hidb = W16 + 5 * NQ;    // bf16 hidden
    unsigned short* wqt  = W16 + 6 * NQ;    // [Wq|Wk|Wv]^T contiguous 2304x768
    unsigned short* wkt  = wqt + 589824;
    unsigned short* wvt  = wkt + 589824;
    unsigned short* wot  = wvt + 589824;
    unsigned short* wit  = wot + 589824;    // 2359296
    unsigned short* wo2t = wit + 2359296;   // 2359296 -> ends at u16 44826624
    float* tmp   = (float*)(W16 + 44826624);  // attn_out fp32 -> ends u16 57409536
    float* partB1 = (float*)(W16 + 57409536); // Wo2 split slice1 -> ends u16 69992448
    float* bcat  = (float*)(W16 + 69992448);  // 2304 fp32
    // aliases over dead regions:
    float* partA0 = (float*)W16;                  // Wo slice0 (over qb,kb)
    float* partA1 = (float*)(W16 + 2 * NQ);       // Wo slice1 (over vb,vtb)
    unsigned short* interb = W16;                 // Wi out (over qb..vtb)
    unsigned short* attnb  = hidb;                // LN1 bf16 (over hidb)
    float* partB0 = (float*)(W16 + 4 * NQ);       // Wo2 slice0 (over ctxb,hidb)
    (void)ws_size; (void)in_sizes; (void)n_in; (void)out_size;

    // fused prep: 6 transposes (+0.125 fold into Wq) + bcat (+0.125 bq) + conv
    prep_k<<<dim3(13065), dim3(32, 8), 0, stream>>>(
        Wq, Wk, Wv, Wo, Wi, Wo2, wqt, wkt, wvt, wot, wit, wo2t,
        bq, bk, bv, bcat, hid, hidb);

    dim3 blk(256);

    // fused QKV: one GEMM, N = 2304, scatter to qb/kb/vb
    gemm_bf<2><<<dim3(1152), blk, 0, stream>>>(hidb, wqt, bcat, qb,
                                               M, 2304, 768, 18);

    vt_k<<<dim3(128, 24), blk, 0, stream>>>(vb, vtb);

    // fused band + global attention (glob blocks first for overlap)
    attn_k<<<dim3(792), blk, 0, stream>>>(qb, kb, vtb, am, ctxb);

    // Wo split-K x2 -> partA0/partA1 ; LN1 fuses reduce+bias+resid
    gemm_sp<<<dim3(768), blk, 0, stream>>>(ctxb, wot, partA0, partA1,
                                           M, 768, 384, 6, 384);
    ln2p_k<<<dim3(M), blk, 0, stream>>>(partA0, partA1, bo, hid,
                                        tmp, attnb, ln1g, ln1b);

    // inter = gelu(attn_out @ Wi + bi)
    gemm_bf<1><<<dim3(1536), blk, 0, stream>>>(attnb, wit, bi, interb,
                                               M, 3072, 768, 24);

    // Wo2 split-K x2 -> partB0/partB1 ; LN2 fuses reduce+bias+resid
    gemm_sp<<<dim3(768), blk, 0, stream>>>(interb, wo2t, partB0, partB1,
                                           M, 768, 1536, 6, 384);
    ln2p_k<<<dim3(M), blk, 0, stream>>>(partB0, partB1, bo2, tmp,
                                        (float*)d_out, nullptr, ln2g, ln2b);
}

// Round 4
// 410.147 us; speedup vs baseline: 1.1603x; 1.0042x over previous
//
#include <hip/hip_runtime.h>
#include <math.h>

#define NHEAD 12
#define DH 64
#define S_LEN 4096
#define B_SZ 2
#define D_MODEL 768
#define FF_DIM 3072
#define WINSZ 128
#define NGLB 32
#define NEGV -1e9f
#define NQC 6291456L

typedef __attribute__((ext_vector_type(8))) short bf16x8;
typedef __attribute__((ext_vector_type(4))) float floatx4;

__device__ __forceinline__ unsigned short f2bf(float x) {
    union { float f; unsigned u; } v; v.f = x;
    unsigned r = v.u + 0x7fffu + ((v.u >> 16) & 1u);
    return (unsigned short)(r >> 16);
}
__device__ __forceinline__ float bf2f(unsigned short x) {
    union { unsigned u; float f; } v; v.u = ((unsigned)x) << 16;
    return v.f;
}

__device__ __forceinline__ void async_copy16(const unsigned short* g, unsigned short* l) {
    __builtin_amdgcn_global_load_lds(
        (const __attribute__((address_space(1))) void*)g,
        (__attribute__((address_space(3))) void*)l, 16, 0, 0);
}

// ---------------------------------------------------------------------------
// Fused prep: 6 weight transposes (fp32 KxN -> bf16 NxK, Wq scaled 0.125)
// + bias concat (bq scaled 0.125) + hidden fp32->bf16 conversion.
// Block ranges: [0,6912) transposes, [6912,6921) bcat, [6921,13065) conv.
// ---------------------------------------------------------------------------
__global__ __launch_bounds__(256) void prep_k(
    const float* __restrict__ Wq, const float* __restrict__ Wk,
    const float* __restrict__ Wv, const float* __restrict__ Wo,
    const float* __restrict__ Wi, const float* __restrict__ Wo2,
    unsigned short* __restrict__ wqt, unsigned short* __restrict__ wkt,
    unsigned short* __restrict__ wvt, unsigned short* __restrict__ wot,
    unsigned short* __restrict__ wit, unsigned short* __restrict__ wo2t,
    const float* __restrict__ bq, const float* __restrict__ bk,
    const float* __restrict__ bv, float* __restrict__ bcat,
    const float* __restrict__ hid, unsigned short* __restrict__ hidb)
{
    __shared__ float tile[32][33];
    const int bid = blockIdx.x;
    const int tx = threadIdx.x, ty = threadIdx.y;

    if (bid < 6912) {
        const float* src; unsigned short* dst; int K, N, nx, local; float scale = 1.f;
        if (bid < 576)       { src = Wq;  dst = wqt;  K = 768;  N = 768;  nx = 24; local = bid;        scale = 0.125f; }
        else if (bid < 1152) { src = Wk;  dst = wkt;  K = 768;  N = 768;  nx = 24; local = bid - 576;  }
        else if (bid < 1728) { src = Wv;  dst = wvt;  K = 768;  N = 768;  nx = 24; local = bid - 1152; }
        else if (bid < 2304) { src = Wo;  dst = wot;  K = 768;  N = 768;  nx = 24; local = bid - 1728; }
        else if (bid < 4608) { src = Wi;  dst = wit;  K = 768;  N = 3072; nx = 96; local = bid - 2304; }
        else                 { src = Wo2; dst = wo2t; K = 3072; N = 768;  nx = 24; local = bid - 4608; }
        const int n0 = (local % nx) * 32, k0 = (local / nx) * 32;
#pragma unroll
        for (int i = 0; i < 4; ++i)
            tile[ty + 8 * i][tx] = src[(long)(k0 + ty + 8 * i) * N + n0 + tx];
        __syncthreads();
#pragma unroll
        for (int i = 0; i < 4; ++i)
            dst[(long)(n0 + ty + 8 * i) * K + k0 + tx] = f2bf(tile[tx][ty + 8 * i] * scale);
    } else if (bid < 6921) {
        const int t = ty * 32 + tx;
        const int i = (bid - 6912) * 256 + t;
        if (i < 768) bcat[i] = bq[i] * 0.125f;
        else if (i < 1536) bcat[i] = bk[i - 768];
        else if (i < 2304) bcat[i] = bv[i - 1536];
    } else {
        const int t = ty * 32 + tx;
        const long i = ((long)(bid - 6921) * 256 + t) * 4;
        float4 v = *(const float4*)(hid + i);
        ushort4 o;
        o.x = f2bf(v.x); o.y = f2bf(v.y); o.z = f2bf(v.z); o.w = f2bf(v.w);
        *(ushort4*)(hidb + i) = o;
    }
}

// ---------------------------------------------------------------------------
// V (B,NH,S,DH) bf16 -> Vt (B,NH,DH,S) bf16
// ---------------------------------------------------------------------------
__global__ __launch_bounds__(256) void vt_k(
    const unsigned short* __restrict__ v, unsigned short* __restrict__ vt)
{
    const int bh = blockIdx.y;
    const int s0 = blockIdx.x * 32;
    const int w = threadIdx.x >> 6, lane = threadIdx.x & 63;
    const unsigned short* src = v + ((long)bh * S_LEN + s0 + w * 8) * DH + lane;
    unsigned short r[8];
#pragma unroll
    for (int j = 0; j < 8; ++j) r[j] = src[j * DH];
    unsigned short* dst = vt + ((long)bh * DH + lane) * S_LEN + s0 + w * 8;
    ushort4 lo, hi;
    lo.x = r[0]; lo.y = r[1]; lo.z = r[2]; lo.w = r[3];
    hi.x = r[4]; hi.y = r[5]; hi.z = r[6]; hi.w = r[7];
    *(ushort4*)dst = lo;
    *(ushort4*)(dst + 4) = hi;
}

// ---------------------------------------------------------------------------
// bf16 MFMA GEMM, 3-buffer rotation, prefetch depth 2, counted vmcnt (T4):
// iter t: issue tile t+2 -> ds_read+MFMA buf[t%3] -> s_waitcnt vmcnt(4)
// (tile t+1 landed, t+2 in flight) -> raw s_barrier. Loads get ~2 compute
// phases to land; vmcnt never drains to 0 in steady state. LDS 3x16 KiB.
// Safety: ds_reads of buf[t%3] are consumed by MFMAs (compiler lgkmcnt)
// before the barrier, so rewriting that buffer at iter t+1 is race-free.
// EPI 1: gelu -> bf16
// EPI 2: fused QKV scatter: part=n/768 (q|k|v) -> bf16 (Q scale pre-folded)
// ---------------------------------------------------------------------------
template <int EPI>
__global__ __launch_bounds__(256) void gemm_bf(
    const unsigned short* __restrict__ A, const unsigned short* __restrict__ BT,
    const float* __restrict__ bias, void* __restrict__ out,
    int M, int N, int K, int nx)
{
    __shared__ unsigned short As[3][128 * 32];
    __shared__ unsigned short Bs[3][128 * 32];
    const int tid = threadIdx.x;
    const int wave = tid >> 6, lane = tid & 63;
    const int t8 = (blockIdx.x & 7) * (gridDim.x >> 3) + (blockIdx.x >> 3);
    const int m0 = (t8 / nx) * 128, n0 = (t8 % nx) * 128;
    const int wr = (wave >> 1) * 64, wc = (wave & 1) * 64;

    floatx4 acc[4][4];
#pragma unroll
    for (int i = 0; i < 4; ++i)
#pragma unroll
        for (int j = 0; j < 4; ++j) acc[i][j] = (floatx4){0.f, 0.f, 0.f, 0.f};

    const int srow = lane >> 2;
    const int schk = (((lane & 3) ^ (srow & 3))) * 8;   // XOR-swizzled stage
    const int r = lane & 15;
    const int q8 = ((lane >> 4) ^ (lane & 3)) * 8;      // XOR-swizzled read

    const int NT = K >> 5;
    const unsigned short* aSrc0 = A  + (long)(m0 + wave * 32 + srow) * K + schk;
    const unsigned short* aSrc1 = A  + (long)(m0 + wave * 32 + 16 + srow) * K + schk;
    const unsigned short* bSrc0 = BT + (long)(n0 + wave * 32 + srow) * K + schk;
    const unsigned short* bSrc1 = BT + (long)(n0 + wave * 32 + 16 + srow) * K + schk;
    const int g0 = wave * 1024, g1 = wave * 1024 + 512;

    // prologue: stage tiles 0 and 1
    async_copy16(aSrc0, &As[0][g0]);
    async_copy16(bSrc0, &Bs[0][g0]);
    async_copy16(aSrc1, &As[0][g1]);
    async_copy16(bSrc1, &Bs[0][g1]);
    if (NT > 1) {
        async_copy16(aSrc0 + 32, &As[1][g0]);
        async_copy16(bSrc0 + 32, &Bs[1][g0]);
        async_copy16(aSrc1 + 32, &As[1][g1]);
        async_copy16(bSrc1 + 32, &Bs[1][g1]);
        asm volatile("s_waitcnt vmcnt(4)" ::: "memory");
    } else {
        asm volatile("s_waitcnt vmcnt(0)" ::: "memory");
    }
    __builtin_amdgcn_s_barrier();
    __builtin_amdgcn_sched_barrier(0);

    int cur = 0;
    for (int t = 0; t < NT; ++t) {
        if (t + 2 < NT) {
            int nb = cur + 2; if (nb >= 3) nb -= 3;
            const int k0 = (t + 2) << 5;
            async_copy16(aSrc0 + k0, &As[nb][g0]);
            async_copy16(bSrc0 + k0, &Bs[nb][g0]);
            async_copy16(aSrc1 + k0, &As[nb][g1]);
            async_copy16(bSrc1 + k0, &Bs[nb][g1]);
        }
        __builtin_amdgcn_sched_barrier(0);

        bf16x8 af[4], bfr[4];
#pragma unroll
        for (int i = 0; i < 4; ++i) {
            af[i]  = *(const bf16x8*)&As[cur][(wr + i * 16 + r) * 32 + q8];
            bfr[i] = *(const bf16x8*)&Bs[cur][(wc + i * 16 + r) * 32 + q8];
        }
        __builtin_amdgcn_s_setprio(1);
#pragma unroll
        for (int i = 0; i < 4; ++i)
#pragma unroll
            for (int j = 0; j < 4; ++j)
                acc[i][j] = __builtin_amdgcn_mfma_f32_16x16x32_bf16(
                    af[i], bfr[j], acc[i][j], 0, 0, 0);
        __builtin_amdgcn_s_setprio(0);
        __builtin_amdgcn_sched_barrier(0);
        if (t + 2 < NT) {
            asm volatile("s_waitcnt vmcnt(4)" ::: "memory");
            __builtin_amdgcn_s_barrier();
        } else if (t + 1 < NT) {
            asm volatile("s_waitcnt vmcnt(0)" ::: "memory");
            __builtin_amdgcn_s_barrier();
        }
        __builtin_amdgcn_sched_barrier(0);
        if (++cur == 3) cur = 0;
    }

    const int col_l = lane & 15, row_l = (lane >> 4) * 4;
#pragma unroll
    for (int i = 0; i < 4; ++i) {
#pragma unroll
        for (int j = 0; j < 4; ++j) {
            const int n = n0 + wc + j * 16 + col_l;
            const float bv = bias[n];
#pragma unroll
            for (int rg = 0; rg < 4; ++rg) {
                const int m = m0 + wr + i * 16 + row_l + rg;
                float v = acc[i][j][rg] + bv;
                if (EPI == 1) {
                    v = 0.5f * v * (1.f + erff(v * 0.70710678118654752f));
                    ((unsigned short*)out)[(long)m * N + n] = f2bf(v);
                } else {
                    const int bb = m >> 12, s = m & 4095;
                    const int part = n / 768;          // 0=q, 1=k, 2=v
                    const int nn = n - part * 768;
                    const int hh = nn >> 6, dh = nn & 63;
                    ((unsigned short*)out)[(long)part * NQC +
                        (((long)bb * NHEAD + hh) * S_LEN + s) * DH + dh] = f2bf(v);
                }
            }
        }
    }
}

// ---------------------------------------------------------------------------
// Split-K (x2) bf16 MFMA GEMM, same 3-buffer counted-vmcnt pipeline. Raw
// fp32 partials; reduction happens inside ln2p_k.
// ---------------------------------------------------------------------------
__global__ __launch_bounds__(256) void gemm_sp(
    const unsigned short* __restrict__ A, const unsigned short* __restrict__ BT,
    float* __restrict__ p0, float* __restrict__ p1,
    int M, int N, int K2, int nx, int ntile)
{
    __shared__ unsigned short As[3][128 * 32];
    __shared__ unsigned short Bs[3][128 * 32];
    const int tid = threadIdx.x;
    const int wave = tid >> 6, lane = tid & 63;
    const int t8 = (blockIdx.x & 7) * (gridDim.x >> 3) + (blockIdx.x >> 3);
    const int slice = t8 >= ntile;
    const int tile = t8 - slice * ntile;
    const int m0 = (tile / nx) * 128, n0 = (tile % nx) * 128;
    const int kbeg = slice * K2;
    float* P = slice ? p1 : p0;
    const int wr = (wave >> 1) * 64, wc = (wave & 1) * 64;

    floatx4 acc[4][4];
#pragma unroll
    for (int i = 0; i < 4; ++i)
#pragma unroll
        for (int j = 0; j < 4; ++j) acc[i][j] = (floatx4){0.f, 0.f, 0.f, 0.f};

    const int srow = lane >> 2;
    const int schk = (((lane & 3) ^ (srow & 3))) * 8;
    const int r = lane & 15;
    const int q8 = ((lane >> 4) ^ (lane & 3)) * 8;
    const long Kl = (long)K2 * 2;

    const int NT = K2 >> 5;
    const unsigned short* aSrc0 = A  + (long)(m0 + wave * 32 + srow) * Kl + kbeg + schk;
    const unsigned short* aSrc1 = A  + (long)(m0 + wave * 32 + 16 + srow) * Kl + kbeg + schk;
    const unsigned short* bSrc0 = BT + (long)(n0 + wave * 32 + srow) * Kl + kbeg + schk;
    const unsigned short* bSrc1 = BT + (long)(n0 + wave * 32 + 16 + srow) * Kl + kbeg + schk;
    const int g0 = wave * 1024, g1 = wave * 1024 + 512;

    async_copy16(aSrc0, &As[0][g0]);
    async_copy16(bSrc0, &Bs[0][g0]);
    async_copy16(aSrc1, &As[0][g1]);
    async_copy16(bSrc1, &Bs[0][g1]);
    if (NT > 1) {
        async_copy16(aSrc0 + 32, &As[1][g0]);
        async_copy16(bSrc0 + 32, &Bs[1][g0]);
        async_copy16(aSrc1 + 32, &As[1][g1]);
        async_copy16(bSrc1 + 32, &Bs[1][g1]);
        asm volatile("s_waitcnt vmcnt(4)" ::: "memory");
    } else {
        asm volatile("s_waitcnt vmcnt(0)" ::: "memory");
    }
    __builtin_amdgcn_s_barrier();
    __builtin_amdgcn_sched_barrier(0);

    int cur = 0;
    for (int t = 0; t < NT; ++t) {
        if (t + 2 < NT) {
            int nb = cur + 2; if (nb >= 3) nb -= 3;
            const int k0 = (t + 2) << 5;
            async_copy16(aSrc0 + k0, &As[nb][g0]);
            async_copy16(bSrc0 + k0, &Bs[nb][g0]);
            async_copy16(aSrc1 + k0, &As[nb][g1]);
            async_copy16(bSrc1 + k0, &Bs[nb][g1]);
        }
        __builtin_amdgcn_sched_barrier(0);

        bf16x8 af[4], bfr[4];
#pragma unroll
        for (int i = 0; i < 4; ++i) {
            af[i]  = *(const bf16x8*)&As[cur][(wr + i * 16 + r) * 32 + q8];
            bfr[i] = *(const bf16x8*)&Bs[cur][(wc + i * 16 + r) * 32 + q8];
        }
        __builtin_amdgcn_s_setprio(1);
#pragma unroll
        for (int i = 0; i < 4; ++i)
#pragma unroll
            for (int j = 0; j < 4; ++j)
                acc[i][j] = __builtin_amdgcn_mfma_f32_16x16x32_bf16(
                    af[i], bfr[j], acc[i][j], 0, 0, 0);
        __builtin_amdgcn_s_setprio(0);
        __builtin_amdgcn_sched_barrier(0);
        if (t + 2 < NT) {
            asm volatile("s_waitcnt vmcnt(4)" ::: "memory");
            __builtin_amdgcn_s_barrier();
        } else if (t + 1 < NT) {
            asm volatile("s_waitcnt vmcnt(0)" ::: "memory");
            __builtin_amdgcn_s_barrier();
        }
        __builtin_amdgcn_sched_barrier(0);
        if (++cur == 3) cur = 0;
    }

    const int col_l = lane & 15, row_l = (lane >> 4) * 4;
#pragma unroll
    for (int i = 0; i < 4; ++i)
#pragma unroll
        for (int j = 0; j < 4; ++j) {
            const int n = n0 + wc + j * 16 + col_l;
#pragma unroll
            for (int rg = 0; rg < 4; ++rg) {
                const int m = m0 + wr + i * 16 + row_l + rg;
                P[(long)m * N + n] = acc[i][j][rg];
            }
        }
}

// ---------------------------------------------------------------------------
// Fused attention: blocks [0,24) = global-query path (4 waves, 16 iters),
// blocks [24,792) = band path (b,h,chunk; 4 waves x 32 queries).
// Glob blocks launch FIRST so they overlap the band wave-front.
// Band suppresses stores for q0 < NGLB (those rows belong to glob) -> no race.
// ---------------------------------------------------------------------------
__global__ __launch_bounds__(256) void attn_k(
    const unsigned short* __restrict__ q, const unsigned short* __restrict__ k,
    const unsigned short* __restrict__ vt, const float* __restrict__ am,
    unsigned short* __restrict__ ctx)
{
    __shared__ __align__(16) unsigned char smem[28800];
    const int blk = blockIdx.x;
    const int tid = threadIdx.x;
    const int wave = tid >> 6, lane = tid & 63;
    const int ln15 = lane & 15, ln4 = lane >> 4;

    if (blk >= 24) {
        // ---------------- band path ----------------
        unsigned short* Ks = (unsigned short*)smem;            // 32*72
        unsigned short* Vs = Ks + 32 * 72;                     // 64*40
        unsigned short* Ps = Vs + 64 * 40;                     // [4][32*40]

        const int bb = blk - 24;
        const int c = bb & 31;
        const int h = (bb >> 5) % NHEAD;
        const int b = bb / (32 * NHEAD);
        const long bh = (long)b * NHEAD + h;

        const unsigned short* kh  = k + bh * S_LEN * DH;
        const unsigned short* vth = vt + bh * (long)DH * S_LEN;
        const float* amb = am + (long)b * S_LEN;

        const int q0 = c * WINSZ + wave * 32;

        bf16x8 qf[2][2];
#pragma unroll
        for (int nt = 0; nt < 2; ++nt)
#pragma unroll
            for (int ks = 0; ks < 2; ++ks)
                qf[nt][ks] = *(const bf16x8*)(q + (bh * S_LEN + q0 + nt * 16 + ln15) * DH
                                              + ks * 32 + ln4 * 8);

        floatx4 o[4][2];
#pragma unroll
        for (int mt = 0; mt < 4; ++mt)
#pragma unroll
            for (int nt = 0; nt < 2; ++nt) o[mt][nt] = (floatx4){0.f, 0.f, 0.f, 0.f};
        float m_r[2] = {-1e30f, -1e30f}, l_r[2] = {0.f, 0.f};

        const int sk_key = tid >> 3, sk_ch = tid & 7;
        const int sv_dim = tid & 63, sv_ch = tid >> 6;
        const bf16x8 zero8 = {0, 0, 0, 0, 0, 0, 0, 0};

        for (int tile = 0; tile < 13; ++tile) {
            const bool glob = (tile == 12);
            const int kbase = glob ? 0 : (c * WINSZ - WINSZ + tile * 32);

            __syncthreads();
            {
                int kpos = kbase + sk_key;
                bf16x8 val = zero8;
                if ((unsigned)kpos < (unsigned)S_LEN)
                    val = *(const bf16x8*)(kh + (long)kpos * DH + sk_ch * 8);
                *(bf16x8*)(&Ks[sk_key * 72 + sk_ch * 8]) = val;
            }
            {
                int kc = kbase + sv_ch * 8;
                bf16x8 val = zero8;
                if (kc >= 0 && kc + 8 <= S_LEN)
                    val = *(const bf16x8*)(vth + (long)sv_dim * S_LEN + kc);
                *(bf16x8*)(&Vs[sv_dim * 40 + sv_ch * 8]) = val;
            }
            __syncthreads();

            bf16x8 ak[2][2];
#pragma unroll
            for (int mt = 0; mt < 2; ++mt)
#pragma unroll
                for (int ks = 0; ks < 2; ++ks)
                    ak[mt][ks] = *(const bf16x8*)(&Ks[(mt * 16 + ln15) * 72 + ks * 32 + ln4 * 8]);

            floatx4 s[2][2];
#pragma unroll
            for (int mt = 0; mt < 2; ++mt)
#pragma unroll
                for (int nt = 0; nt < 2; ++nt) {
                    floatx4 acc = (floatx4){0.f, 0.f, 0.f, 0.f};
                    acc = __builtin_amdgcn_mfma_f32_16x16x32_bf16(ak[mt][0], qf[nt][0], acc, 0, 0, 0);
                    acc = __builtin_amdgcn_mfma_f32_16x16x32_bf16(ak[mt][1], qf[nt][1], acc, 0, 0, 0);
                    s[mt][nt] = acc;
                }

#pragma unroll
            for (int mt = 0; mt < 2; ++mt) {
                const int kp0 = kbase + mt * 16 + ln4 * 4;
#pragma unroll
                for (int rg = 0; rg < 4; ++rg) {
                    const int kpos = kp0 + rg;
                    const bool kin = (unsigned)kpos < (unsigned)S_LEN;
                    const float amv = kin ? amb[kpos] : 0.f;
#pragma unroll
                    for (int nt = 0; nt < 2; ++nt) {
                        const int qpos = q0 + nt * 16 + ln15;
                        const int dlt = kpos > qpos ? kpos - qpos : qpos - kpos;
                        const bool valid = glob || (kpos >= NGLB && kin && dlt <= WINSZ);
                        s[mt][nt][rg] = valid ? s[mt][nt][rg] + amv : NEGV;
                    }
                }
            }

            float alpha[2];
#pragma unroll
            for (int nt = 0; nt < 2; ++nt) {
                float mx = s[0][nt][0];
#pragma unroll
                for (int rg = 1; rg < 4; ++rg) mx = fmaxf(mx, s[0][nt][rg]);
#pragma unroll
                for (int rg = 0; rg < 4; ++rg) mx = fmaxf(mx, s[1][nt][rg]);
                mx = fmaxf(mx, __shfl_xor(mx, 16));
                mx = fmaxf(mx, __shfl_xor(mx, 32));
                const float mn = fmaxf(m_r[nt], mx);
                alpha[nt] = __expf(m_r[nt] - mn);
                m_r[nt] = mn;
            }

#pragma unroll
            for (int nt = 0; nt < 2; ++nt) {
                float sum = 0.f;
#pragma unroll
                for (int mt = 0; mt < 2; ++mt) {
                    ushort4 pk;
#pragma unroll
                    for (int rg = 0; rg < 4; ++rg) {
                        const float p = __expf(s[mt][nt][rg] - m_r[nt]);
                        sum += p;
                        ((unsigned short*)&pk)[rg] = f2bf(p);
                    }
                    *(ushort4*)(&Ps[wave * 1280 + (nt * 16 + ln15) * 40 + mt * 16 + ln4 * 4]) = pk;
                }
                sum += __shfl_xor(sum, 16);
                sum += __shfl_xor(sum, 32);
                l_r[nt] = l_r[nt] * alpha[nt] + sum;
            }

#pragma unroll
            for (int mt = 0; mt < 4; ++mt)
#pragma unroll
                for (int nt = 0; nt < 2; ++nt)
#pragma unroll
                    for (int rg = 0; rg < 4; ++rg) o[mt][nt][rg] *= alpha[nt];

            bf16x8 av[4], bp[2];
#pragma unroll
            for (int mt = 0; mt < 4; ++mt)
                av[mt] = *(const bf16x8*)(&Vs[(mt * 16 + ln15) * 40 + ln4 * 8]);
#pragma unroll
            for (int nt = 0; nt < 2; ++nt)
                bp[nt] = *(const bf16x8*)(&Ps[wave * 1280 + (nt * 16 + ln15) * 40 + ln4 * 8]);
#pragma unroll
            for (int mt = 0; mt < 4; ++mt)
#pragma unroll
                for (int nt = 0; nt < 2; ++nt)
                    o[mt][nt] = __builtin_amdgcn_mfma_f32_16x16x32_bf16(
                        av[mt], bp[nt], o[mt][nt], 0, 0, 0);
        }

        if (q0 >= NGLB) {
            const float inv0 = 1.f / l_r[0], inv1 = 1.f / l_r[1];
#pragma unroll
            for (int nt = 0; nt < 2; ++nt) {
                const float inv = nt ? inv1 : inv0;
                const long row = (long)b * S_LEN + q0 + nt * 16 + ln15;
#pragma unroll
                for (int mt = 0; mt < 4; ++mt) {
                    ushort4 ov;
#pragma unroll
                    for (int rg = 0; rg < 4; ++rg)
                        ((unsigned short*)&ov)[rg] = f2bf(o[mt][nt][rg] * inv);
                    *(ushort4*)(ctx + row * D_MODEL + h * DH + mt * 16 + ln4 * 4) = ov;
                }
            }
        }
    } else {
        // ---------------- global-query path (4 waves, 16 iters) ----------------
        unsigned short* Psg = (unsigned short*)smem;           // [4][32*72]
        float* Om   = (float*)(smem + 18432);                  // 64*36
        float* mW   = (float*)(smem + 27648);                  // [4][32]
        float* lW   = (float*)(smem + 28160);                  // [4][32]
        float* lTot = (float*)(smem + 28672);                  // [32]

        const int bh = blk;
        const int b = bh / NHEAD, h = bh % NHEAD;

        const unsigned short* kh  = k + (long)bh * S_LEN * DH;
        const unsigned short* vth = vt + (long)bh * DH * S_LEN;
        const float* amb = am + (long)b * S_LEN;

        bf16x8 qf[2][2];
#pragma unroll
        for (int nt = 0; nt < 2; ++nt)
#pragma unroll
            for (int ks = 0; ks < 2; ++ks)
                qf[nt][ks] = *(const bf16x8*)(q + ((long)bh * S_LEN + nt * 16 + ln15) * DH
                                              + ks * 32 + ln4 * 8);

        floatx4 o[4][2];
#pragma unroll
        for (int mt = 0; mt < 4; ++mt)
#pragma unroll
            for (int nt = 0; nt < 2; ++nt) o[mt][nt] = (floatx4){0.f, 0.f, 0.f, 0.f};
        float m_r[2] = {-1e30f, -1e30f}, l_r[2] = {0.f, 0.f};

        for (int it = 0; it < 16; ++it) {
            const int kbase = it * 256 + wave * 64;

            bf16x8 ak[4][2];
#pragma unroll
            for (int mt = 0; mt < 4; ++mt)
#pragma unroll
                for (int ks = 0; ks < 2; ++ks)
                    ak[mt][ks] = *(const bf16x8*)(kh + (long)(kbase + mt * 16 + ln15) * DH
                                                  + ks * 32 + ln4 * 8);

            floatx4 s[4][2];
#pragma unroll
            for (int mt = 0; mt < 4; ++mt)
#pragma unroll
                for (int nt = 0; nt < 2; ++nt) {
                    floatx4 acc = (floatx4){0.f, 0.f, 0.f, 0.f};
                    acc = __builtin_amdgcn_mfma_f32_16x16x32_bf16(ak[mt][0], qf[nt][0], acc, 0, 0, 0);
                    acc = __builtin_amdgcn_mfma_f32_16x16x32_bf16(ak[mt][1], qf[nt][1], acc, 0, 0, 0);
                    s[mt][nt] = acc;
                }

#pragma unroll
            for (int mt = 0; mt < 4; ++mt) {
                const int kp0 = kbase + mt * 16 + ln4 * 4;
#pragma unroll
                for (int rg = 0; rg < 4; ++rg) {
                    const float amv = amb[kp0 + rg];
#pragma unroll
                    for (int nt = 0; nt < 2; ++nt) s[mt][nt][rg] += amv;
                }
            }

            float alpha[2];
#pragma unroll
            for (int nt = 0; nt < 2; ++nt) {
                float mx = s[0][nt][0];
#pragma unroll
                for (int mt = 0; mt < 4; ++mt)
#pragma unroll
                    for (int rg = 0; rg < 4; ++rg) mx = fmaxf(mx, s[mt][nt][rg]);
                mx = fmaxf(mx, __shfl_xor(mx, 16));
                mx = fmaxf(mx, __shfl_xor(mx, 32));
                const float mn = fmaxf(m_r[nt], mx);
                alpha[nt] = __expf(m_r[nt] - mn);
                m_r[nt] = mn;
            }

#pragma unroll
            for (int nt = 0; nt < 2; ++nt) {
                float sum = 0.f;
#pragma unroll
                for (int mt = 0; mt < 4; ++mt) {
                    ushort4 pk;
#pragma unroll
                    for (int rg = 0; rg < 4; ++rg) {
                        const float p = __expf(s[mt][nt][rg] - m_r[nt]);
                        sum += p;
                        ((unsigned short*)&pk)[rg] = f2bf(p);
                    }
                    *(ushort4*)(&Psg[wave * 2304 + (nt * 16 + ln15) * 72 + mt * 16 + ln4 * 4]) = pk;
                }
                sum += __shfl_xor(sum, 16);
                sum += __shfl_xor(sum, 32);
                l_r[nt] = l_r[nt] * alpha[nt] + sum;
            }

#pragma unroll
            for (int mt = 0; mt < 4; ++mt)
#pragma unroll
                for (int nt = 0; nt < 2; ++nt)
#pragma unroll
                    for (int rg = 0; rg < 4; ++rg) o[mt][nt][rg] *= alpha[nt];

            bf16x8 av[4][2], bp[2][2];
#pragma unroll
            for (int mt = 0; mt < 4; ++mt)
#pragma unroll
                for (int ks = 0; ks < 2; ++ks)
                    av[mt][ks] = *(const bf16x8*)(vth + (long)(mt * 16 + ln15) * S_LEN
                                                  + kbase + ks * 32 + ln4 * 8);
#pragma unroll
            for (int nt = 0; nt < 2; ++nt)
#pragma unroll
                for (int ks = 0; ks < 2; ++ks)
                    bp[nt][ks] = *(const bf16x8*)(&Psg[wave * 2304 + (nt * 16 + ln15) * 72
                                                  + ks * 32 + ln4 * 8]);
#pragma unroll
            for (int mt = 0; mt < 4; ++mt)
#pragma unroll
                for (int nt = 0; nt < 2; ++nt) {
                    o[mt][nt] = __builtin_amdgcn_mfma_f32_16x16x32_bf16(
                        av[mt][0], bp[nt][0], o[mt][nt], 0, 0, 0);
                    o[mt][nt] = __builtin_amdgcn_mfma_f32_16x16x32_bf16(
                        av[mt][1], bp[nt][1], o[mt][nt], 0, 0, 0);
                }
        }

        if (ln4 == 0) {
#pragma unroll
            for (int nt = 0; nt < 2; ++nt) {
                mW[wave * 32 + nt * 16 + ln15] = m_r[nt];
                lW[wave * 32 + nt * 16 + ln15] = l_r[nt];
            }
        }
        for (int i = tid; i < 64 * 36; i += 256) Om[i] = 0.f;
        __syncthreads();

        float f[2];
#pragma unroll
        for (int nt = 0; nt < 2; ++nt) {
            const int qq = nt * 16 + ln15;
            float mt_ = mW[qq];
#pragma unroll
            for (int w = 1; w < 4; ++w) mt_ = fmaxf(mt_, mW[w * 32 + qq]);
            float lt = 0.f;
#pragma unroll
            for (int w = 0; w < 4; ++w) lt += __expf(mW[w * 32 + qq] - mt_) * lW[w * 32 + qq];
            f[nt] = __expf(m_r[nt] - mt_);
            if (wave == 0 && ln4 == 0) lTot[qq] = lt;
        }
#pragma unroll
        for (int mt = 0; mt < 4; ++mt)
#pragma unroll
            for (int nt = 0; nt < 2; ++nt)
#pragma unroll
                for (int rg = 0; rg < 4; ++rg) o[mt][nt][rg] *= f[nt];

        for (int wv = 0; wv < 4; ++wv) {
            if (wave == wv) {
#pragma unroll
                for (int mt = 0; mt < 4; ++mt)
#pragma unroll
                    for (int nt = 0; nt < 2; ++nt)
#pragma unroll
                        for (int rg = 0; rg < 4; ++rg)
                            Om[(mt * 16 + ln4 * 4 + rg) * 36 + nt * 16 + ln15] += o[mt][nt][rg];
            }
            __syncthreads();
        }

        const int qq = tid >> 3, d0 = (tid & 7) * 8;
        const float inv = 1.f / lTot[qq];
        ushort4 ov0, ov1;
#pragma unroll
        for (int i = 0; i < 4; ++i)
            ((unsigned short*)&ov0)[i] = f2bf(Om[(d0 + i) * 36 + qq] * inv);
#pragma unroll
        for (int i = 0; i < 4; ++i)
            ((unsigned short*)&ov1)[i] = f2bf(Om[(d0 + 4 + i) * 36 + qq] * inv);
        unsigned short* dst = ctx + ((long)b * S_LEN + qq) * D_MODEL + h * DH + d0;
        *(ushort4*)dst = ov0;
        *(ushort4*)(dst + 4) = ov1;
    }
}

// ---------------------------------------------------------------------------
// Fused split-K reduce + bias + residual + LayerNorm. x = p0+p1+bias+resid.
// One block per row (768 cols). Shfl wave-reduce (2 syncs, not 16).
// ---------------------------------------------------------------------------
__global__ __launch_bounds__(256) void ln2p_k(
    const float* __restrict__ p0, const float* __restrict__ p1,
    const float* __restrict__ bias, const float* __restrict__ resid,
    float* __restrict__ out, unsigned short* __restrict__ out_bf,
    const float* __restrict__ gw, const float* __restrict__ bw)
{
    __shared__ float red[8];
    const long base = (long)blockIdx.x * D_MODEL;
    const int t = threadIdx.x;
    const int wv = t >> 6, lane = t & 63;
    float v0 = p0[base + t]       + p1[base + t]       + bias[t]       + resid[base + t];
    float v1 = p0[base + t + 256] + p1[base + t + 256] + bias[t + 256] + resid[base + t + 256];
    float v2 = p0[base + t + 512] + p1[base + t + 512] + bias[t + 512] + resid[base + t + 512];

    float s = v0 + v1 + v2;
#pragma unroll
    for (int off = 32; off; off >>= 1) s += __shfl_xor(s, off);
    if (lane == 0) red[wv] = s;
    __syncthreads();
    const float mu = (red[0] + red[1] + red[2] + red[3]) * (1.f / 768.f);

    const float d0 = v0 - mu, d1 = v1 - mu, d2 = v2 - mu;
    float s2 = d0 * d0 + d1 * d1 + d2 * d2;
#pragma unroll
    for (int off = 32; off; off >>= 1) s2 += __shfl_xor(s2, off);
    if (lane == 0) red[4 + wv] = s2;
    __syncthreads();
    const float var = (red[4] + red[5] + red[6] + red[7]) * (1.f / 768.f);
    const float rs = rsqrtf(var + 1e-12f);

    const float y0 = d0 * rs * gw[t] + bw[t];
    const float y1 = d1 * rs * gw[t + 256] + bw[t + 256];
    const float y2 = d2 * rs * gw[t + 512] + bw[t + 512];
    if (out) {
        float* y = out + base;
        y[t] = y0; y[t + 256] = y1; y[t + 512] = y2;
    }
    if (out_bf) {
        unsigned short* yb = out_bf + base;
        yb[t] = f2bf(y0); yb[t + 256] = f2bf(y1); yb[t + 512] = f2bf(y2);
    }
}

// ---------------------------------------------------------------------------
extern "C" void kernel_launch(void* const* d_in, const int* in_sizes, int n_in,
                              void* d_out, int out_size, void* d_ws, size_t ws_size,
                              hipStream_t stream)
{
    const float* hid  = (const float*)d_in[0];
    const float* am   = (const float*)d_in[1];
    const float* Wq   = (const float*)d_in[2];
    const float* bq   = (const float*)d_in[3];
    const float* Wk   = (const float*)d_in[4];
    const float* bk   = (const float*)d_in[5];
    const float* Wv   = (const float*)d_in[6];
    const float* bv   = (const float*)d_in[7];
    const float* Wo   = (const float*)d_in[8];
    const float* bo   = (const float*)d_in[9];
    const float* ln1g = (const float*)d_in[10];
    const float* ln1b = (const float*)d_in[11];
    const float* Wi   = (const float*)d_in[12];
    const float* bi   = (const float*)d_in[13];
    const float* Wo2  = (const float*)d_in[14];
    const float* bo2  = (const float*)d_in[15];
    const float* ln2g = (const float*)d_in[16];
    const float* ln2b = (const float*)d_in[17];

    const long M  = (long)B_SZ * S_LEN;                 // 8192
    const long NQ = NQC;                                // 6291456

    unsigned short* W16 = (unsigned short*)d_ws;
    unsigned short* qb   = W16;             // bf16 (B,NH,S,DH) — q|k|v contiguous
    unsigned short* kb   = W16 + NQ;
    unsigned short* vb   = W16 + 2 * NQ;
    unsigned short* vtb  = W16 + 3 * NQ;    // bf16 (B,NH,DH,S)
    unsigned short* ctxb = W16 + 4 * NQ;    // bf16 (B,S,768)
    unsigned short* hidb = W16 + 5 * NQ;    // bf16 hidden
    unsigned short* wqt  = W16 + 6 * NQ;    // [Wq|Wk|Wv]^T contiguous 2304x768
    unsigned short* wkt  = wqt + 589824;
    unsigned short* wvt  = wkt + 589824;
    unsigned short* wot  = wvt + 589824;
    unsigned short* wit  = wot + 589824;    // 2359296
    unsigned short* wo2t = wit + 2359296;   // 2359296 -> ends at u16 44826624
    float* tmp   = (float*)(W16 + 44826624);  // attn_out fp32 -> ends u16 57409536
    float* partB1 = (float*)(W16 + 57409536); // Wo2 split slice1 -> ends u16 69992448
    float* bcat  = (float*)(W16 + 69992448);  // 2304 fp32
    // aliases over dead regions:
    float* partA0 = (float*)W16;                  // Wo slice0 (over qb,kb)
    float* partA1 = (float*)(W16 + 2 * NQ);       // Wo slice1 (over vb,vtb)
    unsigned short* interb = W16;                 // Wi out (over qb..vtb)
    unsigned short* attnb  = hidb;                // LN1 bf16 (over hidb)
    float* partB0 = (float*)(W16 + 4 * NQ);       // Wo2 slice0 (over ctxb,hidb)
    (void)ws_size; (void)in_sizes; (void)n_in; (void)out_size;

    // fused prep: 6 transposes (+0.125 fold into Wq) + bcat (+0.125 bq) + conv
    prep_k<<<dim3(13065), dim3(32, 8), 0, stream>>>(
        Wq, Wk, Wv, Wo, Wi, Wo2, wqt, wkt, wvt, wot, wit, wo2t,
        bq, bk, bv, bcat, hid, hidb);

    dim3 blk(256);

    // fused QKV: one GEMM, N = 2304, scatter to qb/kb/vb
    gemm_bf<2><<<dim3(1152), blk, 0, stream>>>(hidb, wqt, bcat, qb,
                                               M, 2304, 768, 18);

    vt_k<<<dim3(128, 24), blk, 0, stream>>>(vb, vtb);

    // fused band + global attention (glob blocks first for overlap)
    attn_k<<<dim3(792), blk, 0, stream>>>(qb, kb, vtb, am, ctxb);

    // Wo split-K x2 -> partA0/partA1 ; LN1 fuses reduce+bias+resid
    gemm_sp<<<dim3(768), blk, 0, stream>>>(ctxb, wot, partA0, partA1,
                                           M, 768, 384, 6, 384);
    ln2p_k<<<dim3(M), blk, 0, stream>>>(partA0, partA1, bo, hid,
                                        tmp, attnb, ln1g, ln1b);

    // inter = gelu(attn_out @ Wi + bi)
    gemm_bf<1><<<dim3(1536), blk, 0, stream>>>(attnb, wit, bi, interb,
                                               M, 3072, 768, 24);

    // Wo2 split-K x2 -> partB0/partB1 ; LN2 fuses reduce+bias+resid
    gemm_sp<<<dim3(768), blk, 0, stream>>>(interb, wo2t, partB0, partB1,
                                           M, 768, 1536, 6, 384);
    ln2p_k<<<dim3(M), blk, 0, stream>>>(partB0, partB1, bo2, tmp,
                                        (float*)d_out, nullptr, ln2g, ln2b);
}

// Round 5
// 405.231 us; speedup vs baseline: 1.1743x; 1.0121x over previous
//
#include <hip/hip_runtime.h>
#include <math.h>

#define NHEAD 12
#define DH 64
#define S_LEN 4096
#define B_SZ 2
#define D_MODEL 768
#define FF_DIM 3072
#define WINSZ 128
#define NGLB 32
#define NEGV -1e9f
#define NQC 6291456L

typedef __attribute__((ext_vector_type(8))) short bf16x8;
typedef __attribute__((ext_vector_type(4))) float floatx4;

__device__ __forceinline__ unsigned short f2bf(float x) {
    union { float f; unsigned u; } v; v.f = x;
    unsigned r = v.u + 0x7fffu + ((v.u >> 16) & 1u);
    return (unsigned short)(r >> 16);
}
__device__ __forceinline__ float bf2f(unsigned short x) {
    union { unsigned u; float f; } v; v.u = ((unsigned)x) << 16;
    return v.f;
}

__device__ __forceinline__ void async_copy16(const unsigned short* g, unsigned short* l) {
    __builtin_amdgcn_global_load_lds(
        (const __attribute__((address_space(1))) void*)g,
        (__attribute__((address_space(3))) void*)l, 16, 0, 0);
}

// ---------------------------------------------------------------------------
// Fused prep: 6 weight transposes (fp32 KxN -> bf16 NxK, Wq scaled 0.125)
// + bias concat (bq scaled 0.125) + hidden fp32->bf16 conversion.
// Block ranges: [0,6912) transposes, [6912,6921) bcat, [6921,13065) conv.
// ---------------------------------------------------------------------------
__global__ __launch_bounds__(256) void prep_k(
    const float* __restrict__ Wq, const float* __restrict__ Wk,
    const float* __restrict__ Wv, const float* __restrict__ Wo,
    const float* __restrict__ Wi, const float* __restrict__ Wo2,
    unsigned short* __restrict__ wqt, unsigned short* __restrict__ wkt,
    unsigned short* __restrict__ wvt, unsigned short* __restrict__ wot,
    unsigned short* __restrict__ wit, unsigned short* __restrict__ wo2t,
    const float* __restrict__ bq, const float* __restrict__ bk,
    const float* __restrict__ bv, float* __restrict__ bcat,
    const float* __restrict__ hid, unsigned short* __restrict__ hidb)
{
    __shared__ float tile[32][33];
    const int bid = blockIdx.x;
    const int tx = threadIdx.x, ty = threadIdx.y;

    if (bid < 6912) {
        const float* src; unsigned short* dst; int K, N, nx, local; float scale = 1.f;
        if (bid < 576)       { src = Wq;  dst = wqt;  K = 768;  N = 768;  nx = 24; local = bid;        scale = 0.125f; }
        else if (bid < 1152) { src = Wk;  dst = wkt;  K = 768;  N = 768;  nx = 24; local = bid - 576;  }
        else if (bid < 1728) { src = Wv;  dst = wvt;  K = 768;  N = 768;  nx = 24; local = bid - 1152; }
        else if (bid < 2304) { src = Wo;  dst = wot;  K = 768;  N = 768;  nx = 24; local = bid - 1728; }
        else if (bid < 4608) { src = Wi;  dst = wit;  K = 768;  N = 3072; nx = 96; local = bid - 2304; }
        else                 { src = Wo2; dst = wo2t; K = 3072; N = 768;  nx = 24; local = bid - 4608; }
        const int n0 = (local % nx) * 32, k0 = (local / nx) * 32;
#pragma unroll
        for (int i = 0; i < 4; ++i)
            tile[ty + 8 * i][tx] = src[(long)(k0 + ty + 8 * i) * N + n0 + tx];
        __syncthreads();
#pragma unroll
        for (int i = 0; i < 4; ++i)
            dst[(long)(n0 + ty + 8 * i) * K + k0 + tx] = f2bf(tile[tx][ty + 8 * i] * scale);
    } else if (bid < 6921) {
        const int t = ty * 32 + tx;
        const int i = (bid - 6912) * 256 + t;
        if (i < 768) bcat[i] = bq[i] * 0.125f;
        else if (i < 1536) bcat[i] = bk[i - 768];
        else if (i < 2304) bcat[i] = bv[i - 1536];
    } else {
        const int t = ty * 32 + tx;
        const long i = ((long)(bid - 6921) * 256 + t) * 4;
        float4 v = *(const float4*)(hid + i);
        ushort4 o;
        o.x = f2bf(v.x); o.y = f2bf(v.y); o.z = f2bf(v.z); o.w = f2bf(v.w);
        *(ushort4*)(hidb + i) = o;
    }
}

// ---------------------------------------------------------------------------
// V (B,NH,S,DH) bf16 -> Vt (B,NH,DH,S) bf16
// ---------------------------------------------------------------------------
__global__ __launch_bounds__(256) void vt_k(
    const unsigned short* __restrict__ v, unsigned short* __restrict__ vt)
{
    const int bh = blockIdx.y;
    const int s0 = blockIdx.x * 32;
    const int w = threadIdx.x >> 6, lane = threadIdx.x & 63;
    const unsigned short* src = v + ((long)bh * S_LEN + s0 + w * 8) * DH + lane;
    unsigned short r[8];
#pragma unroll
    for (int j = 0; j < 8; ++j) r[j] = src[j * DH];
    unsigned short* dst = vt + ((long)bh * DH + lane) * S_LEN + s0 + w * 8;
    ushort4 lo, hi;
    lo.x = r[0]; lo.y = r[1]; lo.z = r[2]; lo.w = r[3];
    hi.x = r[4]; hi.y = r[5]; hi.z = r[6]; hi.w = r[7];
    *(ushort4*)dst = lo;
    *(ushort4*)(dst + 4) = hi;
}

// ---------------------------------------------------------------------------
// bf16 MFMA GEMM, 3-buffer / depth-2 counted-vmcnt pipeline, K-loop
// UNROLLED BY 3 so buffer indices and k-offsets are compile-time:
// ds_read addresses = one VGPR base + imm offsets; global prefetch offsets
// fold into the 13-bit global_load_lds offset field; pointers advance once
// per macro-iter. Cuts per-iter VALU ~5x (round-4 diagnosis: issue-bound,
// no pipe saturated). Wait discipline identical to round 4:
// body u computes buf u, prefetches buf (u+2)%3, ends vmcnt(4)+s_barrier.
// Tail macro: body0 prefetches tile NT-1 (vmcnt(4)); body1 vmcnt(0);
// body2 no trailing wait. Requires NT % 3 == 0 (holds: 12/24/24/48).
// EPI 1: gelu -> bf16
// EPI 2: fused QKV scatter: part=n/768 (q|k|v) -> bf16 (Q scale pre-folded)
// ---------------------------------------------------------------------------
#define GEMM_BODY(U, PF, TAILW)                                              \
    {                                                                        \
        if (PF) {                                                            \
            async_copy16(aSrc0 + (U + 2) * 32, &As[(U + 2) % 3][g0]);        \
            async_copy16(bSrc0 + (U + 2) * 32, &Bs[(U + 2) % 3][g0]);        \
            async_copy16(aSrc1 + (U + 2) * 32, &As[(U + 2) % 3][g1]);        \
            async_copy16(bSrc1 + (U + 2) * 32, &Bs[(U + 2) % 3][g1]);        \
        }                                                                    \
        __builtin_amdgcn_sched_barrier(0);                                   \
        bf16x8 af[4], bfr[4];                                                \
        _Pragma("unroll")                                                    \
        for (int i = 0; i < 4; ++i) {                                        \
            af[i]  = *(const bf16x8*)&As[U][rdA + i * 512];                  \
            bfr[i] = *(const bf16x8*)&Bs[U][rdB + i * 512];                  \
        }                                                                    \
        __builtin_amdgcn_s_setprio(1);                                       \
        _Pragma("unroll")                                                    \
        for (int i = 0; i < 4; ++i)                                          \
            _Pragma("unroll")                                                \
            for (int j = 0; j < 4; ++j)                                      \
                acc[i][j] = __builtin_amdgcn_mfma_f32_16x16x32_bf16(         \
                    af[i], bfr[j], acc[i][j], 0, 0, 0);                      \
        __builtin_amdgcn_s_setprio(0);                                       \
        __builtin_amdgcn_sched_barrier(0);                                   \
        if (TAILW == 2) {                                                    \
            asm volatile("s_waitcnt vmcnt(4)" ::: "memory");                 \
            __builtin_amdgcn_s_barrier();                                    \
        } else if (TAILW == 1) {                                             \
            asm volatile("s_waitcnt vmcnt(0)" ::: "memory");                 \
            __builtin_amdgcn_s_barrier();                                    \
        }                                                                    \
        __builtin_amdgcn_sched_barrier(0);                                   \
    }

template <int EPI>
__global__ __launch_bounds__(256) void gemm_bf(
    const unsigned short* __restrict__ A, const unsigned short* __restrict__ BT,
    const float* __restrict__ bias, void* __restrict__ out,
    int M, int N, int K, int nx)
{
    __shared__ unsigned short As[3][128 * 32];
    __shared__ unsigned short Bs[3][128 * 32];
    const int tid = threadIdx.x;
    const int wave = tid >> 6, lane = tid & 63;
    const int t8 = (blockIdx.x & 7) * (gridDim.x >> 3) + (blockIdx.x >> 3);
    const int m0 = (t8 / nx) * 128, n0 = (t8 % nx) * 128;
    const int wr = (wave >> 1) * 64, wc = (wave & 1) * 64;

    floatx4 acc[4][4];
#pragma unroll
    for (int i = 0; i < 4; ++i)
#pragma unroll
        for (int j = 0; j < 4; ++j) acc[i][j] = (floatx4){0.f, 0.f, 0.f, 0.f};

    const int srow = lane >> 2;
    const int schk = (((lane & 3) ^ (srow & 3))) * 8;   // XOR-swizzled stage
    const int r = lane & 15;
    const int q8 = ((lane >> 4) ^ (lane & 3)) * 8;      // XOR-swizzled read
    const int rdA = (wr + r) * 32 + q8;                 // static ds_read bases
    const int rdB = (wc + r) * 32 + q8;

    const int NT = K >> 5;                              // NT % 3 == 0
    const unsigned short* aSrc0 = A  + (long)(m0 + wave * 32 + srow) * K + schk;
    const unsigned short* aSrc1 = A  + (long)(m0 + wave * 32 + 16 + srow) * K + schk;
    const unsigned short* bSrc0 = BT + (long)(n0 + wave * 32 + srow) * K + schk;
    const unsigned short* bSrc1 = BT + (long)(n0 + wave * 32 + 16 + srow) * K + schk;
    const int g0 = wave * 1024, g1 = wave * 1024 + 512;

    // prologue: stage tiles 0 and 1 into bufs 0 and 1
    async_copy16(aSrc0, &As[0][g0]);
    async_copy16(bSrc0, &Bs[0][g0]);
    async_copy16(aSrc1, &As[0][g1]);
    async_copy16(bSrc1, &Bs[0][g1]);
    async_copy16(aSrc0 + 32, &As[1][g0]);
    async_copy16(bSrc0 + 32, &Bs[1][g0]);
    async_copy16(aSrc1 + 32, &As[1][g1]);
    async_copy16(bSrc1 + 32, &Bs[1][g1]);
    asm volatile("s_waitcnt vmcnt(4)" ::: "memory");
    __builtin_amdgcn_s_barrier();
    __builtin_amdgcn_sched_barrier(0);

    for (int t3 = 0; t3 < NT - 3; t3 += 3) {
        GEMM_BODY(0, 1, 2)
        GEMM_BODY(1, 1, 2)
        GEMM_BODY(2, 1, 2)
        aSrc0 += 96; aSrc1 += 96; bSrc0 += 96; bSrc1 += 96;
    }
    // tail macro-iter (t3 == NT-3): body0 prefetches tile NT-1
    GEMM_BODY(0, 1, 2)
    GEMM_BODY(1, 0, 1)
    GEMM_BODY(2, 0, 0)

    const int col_l = lane & 15, row_l = (lane >> 4) * 4;
#pragma unroll
    for (int i = 0; i < 4; ++i) {
#pragma unroll
        for (int j = 0; j < 4; ++j) {
            const int n = n0 + wc + j * 16 + col_l;
            const float bv = bias[n];
#pragma unroll
            for (int rg = 0; rg < 4; ++rg) {
                const int m = m0 + wr + i * 16 + row_l + rg;
                float v = acc[i][j][rg] + bv;
                if (EPI == 1) {
                    v = 0.5f * v * (1.f + erff(v * 0.70710678118654752f));
                    ((unsigned short*)out)[(long)m * N + n] = f2bf(v);
                } else {
                    const int bb = m >> 12, s = m & 4095;
                    const int part = n / 768;          // 0=q, 1=k, 2=v
                    const int nn = n - part * 768;
                    const int hh = nn >> 6, dh = nn & 63;
                    ((unsigned short*)out)[(long)part * NQC +
                        (((long)bb * NHEAD + hh) * S_LEN + s) * DH + dh] = f2bf(v);
                }
            }
        }
    }
}

// ---------------------------------------------------------------------------
// Split-K (x2) bf16 MFMA GEMM, same unrolled 3-buffer pipeline. Raw fp32
// partials; reduction happens inside ln2p_k.
// ---------------------------------------------------------------------------
__global__ __launch_bounds__(256) void gemm_sp(
    const unsigned short* __restrict__ A, const unsigned short* __restrict__ BT,
    float* __restrict__ p0, float* __restrict__ p1,
    int M, int N, int K2, int nx, int ntile)
{
    __shared__ unsigned short As[3][128 * 32];
    __shared__ unsigned short Bs[3][128 * 32];
    const int tid = threadIdx.x;
    const int wave = tid >> 6, lane = tid & 63;
    const int t8 = (blockIdx.x & 7) * (gridDim.x >> 3) + (blockIdx.x >> 3);
    const int slice = t8 >= ntile;
    const int tile = t8 - slice * ntile;
    const int m0 = (tile / nx) * 128, n0 = (tile % nx) * 128;
    const int kbeg = slice * K2;
    float* P = slice ? p1 : p0;
    const int wr = (wave >> 1) * 64, wc = (wave & 1) * 64;

    floatx4 acc[4][4];
#pragma unroll
    for (int i = 0; i < 4; ++i)
#pragma unroll
        for (int j = 0; j < 4; ++j) acc[i][j] = (floatx4){0.f, 0.f, 0.f, 0.f};

    const int srow = lane >> 2;
    const int schk = (((lane & 3) ^ (srow & 3))) * 8;
    const int r = lane & 15;
    const int q8 = ((lane >> 4) ^ (lane & 3)) * 8;
    const int rdA = (wr + r) * 32 + q8;
    const int rdB = (wc + r) * 32 + q8;
    const long Kl = (long)K2 * 2;

    const int NT = K2 >> 5;                             // NT % 3 == 0
    const unsigned short* aSrc0 = A  + (long)(m0 + wave * 32 + srow) * Kl + kbeg + schk;
    const unsigned short* aSrc1 = A  + (long)(m0 + wave * 32 + 16 + srow) * Kl + kbeg + schk;
    const unsigned short* bSrc0 = BT + (long)(n0 + wave * 32 + srow) * Kl + kbeg + schk;
    const unsigned short* bSrc1 = BT + (long)(n0 + wave * 32 + 16 + srow) * Kl + kbeg + schk;
    const int g0 = wave * 1024, g1 = wave * 1024 + 512;

    async_copy16(aSrc0, &As[0][g0]);
    async_copy16(bSrc0, &Bs[0][g0]);
    async_copy16(aSrc1, &As[0][g1]);
    async_copy16(bSrc1, &Bs[0][g1]);
    async_copy16(aSrc0 + 32, &As[1][g0]);
    async_copy16(bSrc0 + 32, &Bs[1][g0]);
    async_copy16(aSrc1 + 32, &As[1][g1]);
    async_copy16(bSrc1 + 32, &Bs[1][g1]);
    asm volatile("s_waitcnt vmcnt(4)" ::: "memory");
    __builtin_amdgcn_s_barrier();
    __builtin_amdgcn_sched_barrier(0);

    for (int t3 = 0; t3 < NT - 3; t3 += 3) {
        GEMM_BODY(0, 1, 2)
        GEMM_BODY(1, 1, 2)
        GEMM_BODY(2, 1, 2)
        aSrc0 += 96; aSrc1 += 96; bSrc0 += 96; bSrc1 += 96;
    }
    GEMM_BODY(0, 1, 2)
    GEMM_BODY(1, 0, 1)
    GEMM_BODY(2, 0, 0)

    const int col_l = lane & 15, row_l = (lane >> 4) * 4;
#pragma unroll
    for (int i = 0; i < 4; ++i)
#pragma unroll
        for (int j = 0; j < 4; ++j) {
            const int n = n0 + wc + j * 16 + col_l;
#pragma unroll
            for (int rg = 0; rg < 4; ++rg) {
                const int m = m0 + wr + i * 16 + row_l + rg;
                P[(long)m * N + n] = acc[i][j][rg];
            }
        }
}

// ---------------------------------------------------------------------------
// Fused attention: blocks [0,24) = global-query path (4 waves, 16 iters),
// blocks [24,792) = band path (b,h,chunk; 4 waves x 32 queries).
// Glob blocks launch FIRST so they overlap the band wave-front.
// Band suppresses stores for q0 < NGLB (those rows belong to glob) -> no race.
// ---------------------------------------------------------------------------
__global__ __launch_bounds__(256) void attn_k(
    const unsigned short* __restrict__ q, const unsigned short* __restrict__ k,
    const unsigned short* __restrict__ vt, const float* __restrict__ am,
    unsigned short* __restrict__ ctx)
{
    __shared__ __align__(16) unsigned char smem[28800];
    const int blk = blockIdx.x;
    const int tid = threadIdx.x;
    const int wave = tid >> 6, lane = tid & 63;
    const int ln15 = lane & 15, ln4 = lane >> 4;

    if (blk >= 24) {
        // ---------------- band path ----------------
        unsigned short* Ks = (unsigned short*)smem;            // 32*72
        unsigned short* Vs = Ks + 32 * 72;                     // 64*40
        unsigned short* Ps = Vs + 64 * 40;                     // [4][32*40]

        const int bb = blk - 24;
        const int c = bb & 31;
        const int h = (bb >> 5) % NHEAD;
        const int b = bb / (32 * NHEAD);
        const long bh = (long)b * NHEAD + h;

        const unsigned short* kh  = k + bh * S_LEN * DH;
        const unsigned short* vth = vt + bh * (long)DH * S_LEN;
        const float* amb = am + (long)b * S_LEN;

        const int q0 = c * WINSZ + wave * 32;

        bf16x8 qf[2][2];
#pragma unroll
        for (int nt = 0; nt < 2; ++nt)
#pragma unroll
            for (int ks = 0; ks < 2; ++ks)
                qf[nt][ks] = *(const bf16x8*)(q + (bh * S_LEN + q0 + nt * 16 + ln15) * DH
                                              + ks * 32 + ln4 * 8);

        floatx4 o[4][2];
#pragma unroll
        for (int mt = 0; mt < 4; ++mt)
#pragma unroll
            for (int nt = 0; nt < 2; ++nt) o[mt][nt] = (floatx4){0.f, 0.f, 0.f, 0.f};
        float m_r[2] = {-1e30f, -1e30f}, l_r[2] = {0.f, 0.f};

        const int sk_key = tid >> 3, sk_ch = tid & 7;
        const int sv_dim = tid & 63, sv_ch = tid >> 6;
        const bf16x8 zero8 = {0, 0, 0, 0, 0, 0, 0, 0};

        for (int tile = 0; tile < 13; ++tile) {
            const bool glob = (tile == 12);
            const int kbase = glob ? 0 : (c * WINSZ - WINSZ + tile * 32);

            __syncthreads();
            {
                int kpos = kbase + sk_key;
                bf16x8 val = zero8;
                if ((unsigned)kpos < (unsigned)S_LEN)
                    val = *(const bf16x8*)(kh + (long)kpos * DH + sk_ch * 8);
                *(bf16x8*)(&Ks[sk_key * 72 + sk_ch * 8]) = val;
            }
            {
                int kc = kbase + sv_ch * 8;
                bf16x8 val = zero8;
                if (kc >= 0 && kc + 8 <= S_LEN)
                    val = *(const bf16x8*)(vth + (long)sv_dim * S_LEN + kc);
                *(bf16x8*)(&Vs[sv_dim * 40 + sv_ch * 8]) = val;
            }
            __syncthreads();

            bf16x8 ak[2][2];
#pragma unroll
            for (int mt = 0; mt < 2; ++mt)
#pragma unroll
                for (int ks = 0; ks < 2; ++ks)
                    ak[mt][ks] = *(const bf16x8*)(&Ks[(mt * 16 + ln15) * 72 + ks * 32 + ln4 * 8]);

            floatx4 s[2][2];
#pragma unroll
            for (int mt = 0; mt < 2; ++mt)
#pragma unroll
                for (int nt = 0; nt < 2; ++nt) {
                    floatx4 acc = (floatx4){0.f, 0.f, 0.f, 0.f};
                    acc = __builtin_amdgcn_mfma_f32_16x16x32_bf16(ak[mt][0], qf[nt][0], acc, 0, 0, 0);
                    acc = __builtin_amdgcn_mfma_f32_16x16x32_bf16(ak[mt][1], qf[nt][1], acc, 0, 0, 0);
                    s[mt][nt] = acc;
                }

#pragma unroll
            for (int mt = 0; mt < 2; ++mt) {
                const int kp0 = kbase + mt * 16 + ln4 * 4;
#pragma unroll
                for (int rg = 0; rg < 4; ++rg) {
                    const int kpos = kp0 + rg;
                    const bool kin = (unsigned)kpos < (unsigned)S_LEN;
                    const float amv = kin ? amb[kpos] : 0.f;
#pragma unroll
                    for (int nt = 0; nt < 2; ++nt) {
                        const int qpos = q0 + nt * 16 + ln15;
                        const int dlt = kpos > qpos ? kpos - qpos : qpos - kpos;
                        const bool valid = glob || (kpos >= NGLB && kin && dlt <= WINSZ);
                        s[mt][nt][rg] = valid ? s[mt][nt][rg] + amv : NEGV;
                    }
                }
            }

            float alpha[2];
#pragma unroll
            for (int nt = 0; nt < 2; ++nt) {
                float mx = s[0][nt][0];
#pragma unroll
                for (int rg = 1; rg < 4; ++rg) mx = fmaxf(mx, s[0][nt][rg]);
#pragma unroll
                for (int rg = 0; rg < 4; ++rg) mx = fmaxf(mx, s[1][nt][rg]);
                mx = fmaxf(mx, __shfl_xor(mx, 16));
                mx = fmaxf(mx, __shfl_xor(mx, 32));
                const float mn = fmaxf(m_r[nt], mx);
                alpha[nt] = __expf(m_r[nt] - mn);
                m_r[nt] = mn;
            }

#pragma unroll
            for (int nt = 0; nt < 2; ++nt) {
                float sum = 0.f;
#pragma unroll
                for (int mt = 0; mt < 2; ++mt) {
                    ushort4 pk;
#pragma unroll
                    for (int rg = 0; rg < 4; ++rg) {
                        const float p = __expf(s[mt][nt][rg] - m_r[nt]);
                        sum += p;
                        ((unsigned short*)&pk)[rg] = f2bf(p);
                    }
                    *(ushort4*)(&Ps[wave * 1280 + (nt * 16 + ln15) * 40 + mt * 16 + ln4 * 4]) = pk;
                }
                sum += __shfl_xor(sum, 16);
                sum += __shfl_xor(sum, 32);
                l_r[nt] = l_r[nt] * alpha[nt] + sum;
            }

#pragma unroll
            for (int mt = 0; mt < 4; ++mt)
#pragma unroll
                for (int nt = 0; nt < 2; ++nt)
#pragma unroll
                    for (int rg = 0; rg < 4; ++rg) o[mt][nt][rg] *= alpha[nt];

            bf16x8 av[4], bp[2];
#pragma unroll
            for (int mt = 0; mt < 4; ++mt)
                av[mt] = *(const bf16x8*)(&Vs[(mt * 16 + ln15) * 40 + ln4 * 8]);
#pragma unroll
            for (int nt = 0; nt < 2; ++nt)
                bp[nt] = *(const bf16x8*)(&Ps[wave * 1280 + (nt * 16 + ln15) * 40 + ln4 * 8]);
#pragma unroll
            for (int mt = 0; mt < 4; ++mt)
#pragma unroll
                for (int nt = 0; nt < 2; ++nt)
                    o[mt][nt] = __builtin_amdgcn_mfma_f32_16x16x32_bf16(
                        av[mt], bp[nt], o[mt][nt], 0, 0, 0);
        }

        if (q0 >= NGLB) {
            const float inv0 = 1.f / l_r[0], inv1 = 1.f / l_r[1];
#pragma unroll
            for (int nt = 0; nt < 2; ++nt) {
                const float inv = nt ? inv1 : inv0;
                const long row = (long)b * S_LEN + q0 + nt * 16 + ln15;
#pragma unroll
                for (int mt = 0; mt < 4; ++mt) {
                    ushort4 ov;
#pragma unroll
                    for (int rg = 0; rg < 4; ++rg)
                        ((unsigned short*)&ov)[rg] = f2bf(o[mt][nt][rg] * inv);
                    *(ushort4*)(ctx + row * D_MODEL + h * DH + mt * 16 + ln4 * 4) = ov;
                }
            }
        }
    } else {
        // ---------------- global-query path (4 waves, 16 iters) ----------------
        unsigned short* Psg = (unsigned short*)smem;           // [4][32*72]
        float* Om   = (float*)(smem + 18432);                  // 64*36
        float* mW   = (float*)(smem + 27648);                  // [4][32]
        float* lW   = (float*)(smem + 28160);                  // [4][32]
        float* lTot = (float*)(smem + 28672);                  // [32]

        const int bh = blk;
        const int b = bh / NHEAD, h = bh % NHEAD;

        const unsigned short* kh  = k + (long)bh * S_LEN * DH;
        const unsigned short* vth = vt + (long)bh * DH * S_LEN;
        const float* amb = am + (long)b * S_LEN;

        bf16x8 qf[2][2];
#pragma unroll
        for (int nt = 0; nt < 2; ++nt)
#pragma unroll
            for (int ks = 0; ks < 2; ++ks)
                qf[nt][ks] = *(const bf16x8*)(q + ((long)bh * S_LEN + nt * 16 + ln15) * DH
                                              + ks * 32 + ln4 * 8);

        floatx4 o[4][2];
#pragma unroll
        for (int mt = 0; mt < 4; ++mt)
#pragma unroll
            for (int nt = 0; nt < 2; ++nt) o[mt][nt] = (floatx4){0.f, 0.f, 0.f, 0.f};
        float m_r[2] = {-1e30f, -1e30f}, l_r[2] = {0.f, 0.f};

        for (int it = 0; it < 16; ++it) {
            const int kbase = it * 256 + wave * 64;

            bf16x8 ak[4][2];
#pragma unroll
            for (int mt = 0; mt < 4; ++mt)
#pragma unroll
                for (int ks = 0; ks < 2; ++ks)
                    ak[mt][ks] = *(const bf16x8*)(kh + (long)(kbase + mt * 16 + ln15) * DH
                                                  + ks * 32 + ln4 * 8);

            floatx4 s[4][2];
#pragma unroll
            for (int mt = 0; mt < 4; ++mt)
#pragma unroll
                for (int nt = 0; nt < 2; ++nt) {
                    floatx4 acc = (floatx4){0.f, 0.f, 0.f, 0.f};
                    acc = __builtin_amdgcn_mfma_f32_16x16x32_bf16(ak[mt][0], qf[nt][0], acc, 0, 0, 0);
                    acc = __builtin_amdgcn_mfma_f32_16x16x32_bf16(ak[mt][1], qf[nt][1], acc, 0, 0, 0);
                    s[mt][nt] = acc;
                }

#pragma unroll
            for (int mt = 0; mt < 4; ++mt) {
                const int kp0 = kbase + mt * 16 + ln4 * 4;
#pragma unroll
                for (int rg = 0; rg < 4; ++rg) {
                    const float amv = amb[kp0 + rg];
#pragma unroll
                    for (int nt = 0; nt < 2; ++nt) s[mt][nt][rg] += amv;
                }
            }

            float alpha[2];
#pragma unroll
            for (int nt = 0; nt < 2; ++nt) {
                float mx = s[0][nt][0];
#pragma unroll
                for (int mt = 0; mt < 4; ++mt)
#pragma unroll
                    for (int rg = 0; rg < 4; ++rg) mx = fmaxf(mx, s[mt][nt][rg]);
                mx = fmaxf(mx, __shfl_xor(mx, 16));
                mx = fmaxf(mx, __shfl_xor(mx, 32));
                const float mn = fmaxf(m_r[nt], mx);
                alpha[nt] = __expf(m_r[nt] - mn);
                m_r[nt] = mn;
            }

#pragma unroll
            for (int nt = 0; nt < 2; ++nt) {
                float sum = 0.f;
#pragma unroll
                for (int mt = 0; mt < 4; ++mt) {
                    ushort4 pk;
#pragma unroll
                    for (int rg = 0; rg < 4; ++rg) {
                        const float p = __expf(s[mt][nt][rg] - m_r[nt]);
                        sum += p;
                        ((unsigned short*)&pk)[rg] = f2bf(p);
                    }
                    *(ushort4*)(&Psg[wave * 2304 + (nt * 16 + ln15) * 72 + mt * 16 + ln4 * 4]) = pk;
                }
                sum += __shfl_xor(sum, 16);
                sum += __shfl_xor(sum, 32);
                l_r[nt] = l_r[nt] * alpha[nt] + sum;
            }

#pragma unroll
            for (int mt = 0; mt < 4; ++mt)
#pragma unroll
                for (int nt = 0; nt < 2; ++nt)
#pragma unroll
                    for (int rg = 0; rg < 4; ++rg) o[mt][nt][rg] *= alpha[nt];

            bf16x8 av[4][2], bp[2][2];
#pragma unroll
            for (int mt = 0; mt < 4; ++mt)
#pragma unroll
                for (int ks = 0; ks < 2; ++ks)
                    av[mt][ks] = *(const bf16x8*)(vth + (long)(mt * 16 + ln15) * S_LEN
                                                  + kbase + ks * 32 + ln4 * 8);
#pragma unroll
            for (int nt = 0; nt < 2; ++nt)
#pragma unroll
                for (int ks = 0; ks < 2; ++ks)
                    bp[nt][ks] = *(const bf16x8*)(&Psg[wave * 2304 + (nt * 16 + ln15) * 72
                                                  + ks * 32 + ln4 * 8]);
#pragma unroll
            for (int mt = 0; mt < 4; ++mt)
#pragma unroll
                for (int nt = 0; nt < 2; ++nt) {
                    o[mt][nt] = __builtin_amdgcn_mfma_f32_16x16x32_bf16(
                        av[mt][0], bp[nt][0], o[mt][nt], 0, 0, 0);
                    o[mt][nt] = __builtin_amdgcn_mfma_f32_16x16x32_bf16(
                        av[mt][1], bp[nt][1], o[mt][nt], 0, 0, 0);
                }
        }

        if (ln4 == 0) {
#pragma unroll
            for (int nt = 0; nt < 2; ++nt) {
                mW[wave * 32 + nt * 16 + ln15] = m_r[nt];
                lW[wave * 32 + nt * 16 + ln15] = l_r[nt];
            }
        }
        for (int i = tid; i < 64 * 36; i += 256) Om[i] = 0.f;
        __syncthreads();

        float f[2];
#pragma unroll
        for (int nt = 0; nt < 2; ++nt) {
            const int qq = nt * 16 + ln15;
            float mt_ = mW[qq];
#pragma unroll
            for (int w = 1; w < 4; ++w) mt_ = fmaxf(mt_, mW[w * 32 + qq]);
            float lt = 0.f;
#pragma unroll
            for (int w = 0; w < 4; ++w) lt += __expf(mW[w * 32 + qq] - mt_) * lW[w * 32 + qq];
            f[nt] = __expf(m_r[nt] - mt_);
            if (wave == 0 && ln4 == 0) lTot[qq] = lt;
        }
#pragma unroll
        for (int mt = 0; mt < 4; ++mt)
#pragma unroll
            for (int nt = 0; nt < 2; ++nt)
#pragma unroll
                for (int rg = 0; rg < 4; ++rg) o[mt][nt][rg] *= f[nt];

        for (int wv = 0; wv < 4; ++wv) {
            if (wave == wv) {
#pragma unroll
                for (int mt = 0; mt < 4; ++mt)
#pragma unroll
                    for (int nt = 0; nt < 2; ++nt)
#pragma unroll
                        for (int rg = 0; rg < 4; ++rg)
                            Om[(mt * 16 + ln4 * 4 + rg) * 36 + nt * 16 + ln15] += o[mt][nt][rg];
            }
            __syncthreads();
        }

        const int qq = tid >> 3, d0 = (tid & 7) * 8;
        const float inv = 1.f / lTot[qq];
        ushort4 ov0, ov1;
#pragma unroll
        for (int i = 0; i < 4; ++i)
            ((unsigned short*)&ov0)[i] = f2bf(Om[(d0 + i) * 36 + qq] * inv);
#pragma unroll
        for (int i = 0; i < 4; ++i)
            ((unsigned short*)&ov1)[i] = f2bf(Om[(d0 + 4 + i) * 36 + qq] * inv);
        unsigned short* dst = ctx + ((long)b * S_LEN + qq) * D_MODEL + h * DH + d0;
        *(ushort4*)dst = ov0;
        *(ushort4*)(dst + 4) = ov1;
    }
}

// ---------------------------------------------------------------------------
// Fused split-K reduce + bias + residual + LayerNorm. x = p0+p1+bias+resid.
// One block per row (768 cols). Shfl wave-reduce (2 syncs, not 16).
// ---------------------------------------------------------------------------
__global__ __launch_bounds__(256) void ln2p_k(
    const float* __restrict__ p0, const float* __restrict__ p1,
    const float* __restrict__ bias, const float* __restrict__ resid,
    float* __restrict__ out, unsigned short* __restrict__ out_bf,
    const float* __restrict__ gw, const float* __restrict__ bw)
{
    __shared__ float red[8];
    const long base = (long)blockIdx.x * D_MODEL;
    const int t = threadIdx.x;
    const int wv = t >> 6, lane = t & 63;
    float v0 = p0[base + t]       + p1[base + t]       + bias[t]       + resid[base + t];
    float v1 = p0[base + t + 256] + p1[base + t + 256] + bias[t + 256] + resid[base + t + 256];
    float v2 = p0[base + t + 512] + p1[base + t + 512] + bias[t + 512] + resid[base + t + 512];

    float s = v0 + v1 + v2;
#pragma unroll
    for (int off = 32; off; off >>= 1) s += __shfl_xor(s, off);
    if (lane == 0) red[wv] = s;
    __syncthreads();
    const float mu = (red[0] + red[1] + red[2] + red[3]) * (1.f / 768.f);

    const float d0 = v0 - mu, d1 = v1 - mu, d2 = v2 - mu;
    float s2 = d0 * d0 + d1 * d1 + d2 * d2;
#pragma unroll
    for (int off = 32; off; off >>= 1) s2 += __shfl_xor(s2, off);
    if (lane == 0) red[4 + wv] = s2;
    __syncthreads();
    const float var = (red[4] + red[5] + red[6] + red[7]) * (1.f / 768.f);
    const float rs = rsqrtf(var + 1e-12f);

    const float y0 = d0 * rs * gw[t] + bw[t];
    const float y1 = d1 * rs * gw[t + 256] + bw[t + 256];
    const float y2 = d2 * rs * gw[t + 512] + bw[t + 512];
    if (out) {
        float* y = out + base;
        y[t] = y0; y[t + 256] = y1; y[t + 512] = y2;
    }
    if (out_bf) {
        unsigned short* yb = out_bf + base;
        yb[t] = f2bf(y0); yb[t + 256] = f2bf(y1); yb[t + 512] = f2bf(y2);
    }
}

// ---------------------------------------------------------------------------
extern "C" void kernel_launch(void* const* d_in, const int* in_sizes, int n_in,
                              void* d_out, int out_size, void* d_ws, size_t ws_size,
                              hipStream_t stream)
{
    const float* hid  = (const float*)d_in[0];
    const float* am   = (const float*)d_in[1];
    const float* Wq   = (const float*)d_in[2];
    const float* bq   = (const float*)d_in[3];
    const float* Wk   = (const float*)d_in[4];
    const float* bk   = (const float*)d_in[5];
    const float* Wv   = (const float*)d_in[6];
    const float* bv   = (const float*)d_in[7];
    const float* Wo   = (const float*)d_in[8];
    const float* bo   = (const float*)d_in[9];
    const float* ln1g = (const float*)d_in[10];
    const float* ln1b = (const float*)d_in[11];
    const float* Wi   = (const float*)d_in[12];
    const float* bi   = (const float*)d_in[13];
    const float* Wo2  = (const float*)d_in[14];
    const float* bo2  = (const float*)d_in[15];
    const float* ln2g = (const float*)d_in[16];
    const float* ln2b = (const float*)d_in[17];

    const long M  = (long)B_SZ * S_LEN;                 // 8192
    const long NQ = NQC;                                // 6291456

    unsigned short* W16 = (unsigned short*)d_ws;
    unsigned short* qb   = W16;             // bf16 (B,NH,S,DH) — q|k|v contiguous
    unsigned short* kb   = W16 + NQ;
    unsigned short* vb   = W16 + 2 * NQ;
    unsigned short* vtb  = W16 + 3 * NQ;    // bf16 (B,NH,DH,S)
    unsigned short* ctxb = W16 + 4 * NQ;    // bf16 (B,S,768)
    unsigned short* hidb = W16 + 5 * NQ;    // bf16 hidden
    unsigned short* wqt  = W16 + 6 * NQ;    // [Wq|Wk|Wv]^T contiguous 2304x768
    unsigned short* wkt  = wqt + 589824;
    unsigned short* wvt  = wkt + 589824;
    unsigned short* wot  = wvt + 589824;
    unsigned short* wit  = wot + 589824;    // 2359296
    unsigned short* wo2t = wit + 2359296;   // 2359296 -> ends at u16 44826624
    float* tmp   = (float*)(W16 + 44826624);  // attn_out fp32 -> ends u16 57409536
    float* partB1 = (float*)(W16 + 57409536); // Wo2 split slice1 -> ends u16 69992448
    float* bcat  = (float*)(W16 + 69992448);  // 2304 fp32
    // aliases over dead regions:
    float* partA0 = (float*)W16;                  // Wo slice0 (over qb,kb)
    float* partA1 = (float*)(W16 + 2 * NQ);       // Wo slice1 (over vb,vtb)
    unsigned short* interb = W16;                 // Wi out (over qb..vtb)
    unsigned short* attnb  = hidb;                // LN1 bf16 (over hidb)
    float* partB0 = (float*)(W16 + 4 * NQ);       // Wo2 slice0 (over ctxb,hidb)
    (void)ws_size; (void)in_sizes; (void)n_in; (void)out_size;

    // fused prep: 6 transposes (+0.125 fold into Wq) + bcat (+0.125 bq) + conv
    prep_k<<<dim3(13065), dim3(32, 8), 0, stream>>>(
        Wq, Wk, Wv, Wo, Wi, Wo2, wqt, wkt, wvt, wot, wit, wo2t,
        bq, bk, bv, bcat, hid, hidb);

    dim3 blk(256);

    // fused QKV: one GEMM, N = 2304, scatter to qb/kb/vb
    gemm_bf<2><<<dim3(1152), blk, 0, stream>>>(hidb, wqt, bcat, qb,
                                               M, 2304, 768, 18);

    vt_k<<<dim3(128, 24), blk, 0, stream>>>(vb, vtb);

    // fused band + global attention (glob blocks first for overlap)
    attn_k<<<dim3(792), blk, 0, stream>>>(qb, kb, vtb, am, ctxb);

    // Wo split-K x2 -> partA0/partA1 ; LN1 fuses reduce+bias+resid
    gemm_sp<<<dim3(768), blk, 0, stream>>>(ctxb, wot, partA0, partA1,
                                           M, 768, 384, 6, 384);
    ln2p_k<<<dim3(M), blk, 0, stream>>>(partA0, partA1, bo, hid,
                                        tmp, attnb, ln1g, ln1b);

    // inter = gelu(attn_out @ Wi + bi)
    gemm_bf<1><<<dim3(1536), blk, 0, stream>>>(attnb, wit, bi, interb,
                                               M, 3072, 768, 24);

    // Wo2 split-K x2 -> partB0/partB1 ; LN2 fuses reduce+bias+resid
    gemm_sp<<<dim3(768), blk, 0, stream>>>(interb, wo2t, partB0, partB1,
                                           M, 768, 1536, 6, 384);
    ln2p_k<<<dim3(M), blk, 0, stream>>>(partB0, partB1, bo2, tmp,
                                        (float*)d_out, nullptr, ln2g, ln2b);
}